// Round 18
// baseline (276.706 us; speedup 1.0000x reference)
//
#include <hip/hip_runtime.h>
#include <hip/hip_bf16.h>
#include <cstdint>

#define NUM_GRAPHS 128
constexpr float EPSF = 1e-5f;

using short8 = __attribute__((ext_vector_type(8))) short;
using f32x4  = __attribute__((ext_vector_type(4))) float;

// order-preserving float<->uint key (works for negatives)
__device__ __forceinline__ unsigned int enc_key(float f) {
  unsigned int b = __float_as_uint(f);
  return (b & 0x80000000u) ? ~b : (b | 0x80000000u);
}
__device__ __forceinline__ float dec_key(unsigned int k) {
  return __uint_as_float((k & 0x80000000u) ? (k ^ 0x80000000u) : ~k);
}

// manual bf16 RNE conversion (finite values)
__device__ __forceinline__ unsigned int f2bf(float v) {
  unsigned int u = __float_as_uint(v);
  u += 0x7FFFu + ((u >> 16) & 1u);
  return (u >> 16) & 0xFFFFu;
}
__device__ __forceinline__ float bf2f(unsigned int h) {
  return __uint_as_float(h << 16);
}

// swizzled A-plane offset (plane = N x 64 bf16):
//   off(n, f) = (n>>4)*1024 + (f>>3)*128 + (n&15)*8 + (f&7)
__device__ __forceinline__ size_t aswz(int n, int kunit) {
  return ((size_t)(n >> 4) * 8 + kunit) * 128 + (size_t)(n & 15) * 8;
}

__device__ __forceinline__ float4 bnrelu4(float4 v, const float4 A, const float4 B) {
  v.x = fmaxf(fmaf(v.x, A.x, B.x), 0.f);
  v.y = fmaxf(fmaf(v.y, A.y, B.y), 0.f);
  v.z = fmaxf(fmaf(v.z, A.z, B.z), 0.f);
  v.w = fmaxf(fmaf(v.w, A.w, B.w), 0.f);
  return v;
}

// ================= consolidated init: bcnt=0, bnsums=0, pooled keys ==================
__global__ __launch_bounds__(256) void init_kernel(int* __restrict__ bcnt,
                                                   float* __restrict__ bnsum1,
                                                   float* __restrict__ bnsum2,
                                                   float* __restrict__ bnsum3,
                                                   unsigned int* __restrict__ pmax,
                                                   unsigned int* __restrict__ pmin) {
  const int i = blockIdx.x * 256 + threadIdx.x;  // grid covers 65536
  if (i < 256) bcnt[i] = 0;
  if (i < 8 * 32) bnsum1[i] = 0.f;
  if (i < 8 * 128) bnsum2[i] = 0.f;
  if (i < 8 * 1024) bnsum3[i] = 0.f;
  if (i < NUM_GRAPHS * 512) {
    pmax[i] = 0x007FFFFFu;
    pmin[i] = 0xFF800000u;
  }
}

// ================= CSR build (bucketed; bucket = dst>>9, <=256 buckets) =================

__global__ __launch_bounds__(256) void bhist_kernel(const int* __restrict__ dst,
                                                    int* __restrict__ bcnt, int E) {
  __shared__ int hist[256];
  const int t = threadIdx.x;
  const int e0 = blockIdx.x * 8192;
  const int e1 = min(e0 + 8192, E);
  hist[t] = 0;
  __syncthreads();
  for (int e = e0 + t; e < e1; e += 256) atomicAdd(&hist[dst[e] >> 9], 1);
  __syncthreads();
  if (hist[t]) atomicAdd(&bcnt[t], hist[t]);
}

__global__ void bscan_kernel(const int* __restrict__ bcnt, int* __restrict__ bbase,
                             int* __restrict__ bcur, int E) {
  __shared__ int ts[256];
  const int t = threadIdx.x;
  int v = bcnt[t];
  ts[t] = v;
  __syncthreads();
  for (int off = 1; off < 256; off <<= 1) {
    int add = (t >= off) ? ts[t - off] : 0;
    __syncthreads();
    ts[t] += add;
    __syncthreads();
  }
  int excl = ts[t] - v;
  bbase[t] = excl;
  bcur[t] = excl;
  if (t == 255) bbase[256] = E;
}

// pass A: chunk edges, LDS-histogram by bucket, reserve, write packed src|(localdst<<23)
__global__ __launch_bounds__(256) void bucketA_kernel(const int* __restrict__ src,
                                                      const int* __restrict__ dst,
                                                      int* __restrict__ bcur,
                                                      unsigned int* __restrict__ ebuf, int E) {
  __shared__ int hist[256];
  __shared__ int base[256];
  const int t = threadIdx.x;
  const int e0 = blockIdx.x * 8192;
  const int e1 = min(e0 + 8192, E);
  hist[t] = 0;
  __syncthreads();
  for (int e = e0 + t; e < e1; e += 256) atomicAdd(&hist[dst[e] >> 9], 1);
  __syncthreads();
  int c = hist[t];
  base[t] = c ? atomicAdd(&bcur[t], c) : 0;
  hist[t] = 0;
  __syncthreads();
  for (int e = e0 + t; e < e1; e += 256) {
    int d = dst[e];
    int b = d >> 9;
    int p = base[b] + atomicAdd(&hist[b], 1);
    ebuf[p] = (unsigned int)src[e] | ((unsigned int)(d & 511) << 23);
  }
}

// one block per bucket: LDS-stage edges, histogram+scan -> rowptr slice, scatter csr.
__global__ __launch_bounds__(256) void bucketCSR_kernel(
    const unsigned int* __restrict__ ebufp, const int* __restrict__ bbase,
    int* __restrict__ rowptr, int* __restrict__ csr, int N, int E) {
  __shared__ unsigned int eb[12288];
  __shared__ int hist[512];
  __shared__ int ts[256];
  const int b = blockIdx.x;
  const int t = threadIdx.x;
  const int lo = bbase[b], hi = bbase[b + 1];
  const int cnt = hi - lo;
  const bool stage = (cnt <= 12288);
  hist[t] = 0;
  hist[t + 256] = 0;
  __syncthreads();
  if (stage) {
    for (int i = t; i < cnt; i += 256) {
      unsigned int e = ebufp[lo + i];
      eb[i] = e;
      atomicAdd(&hist[e >> 23], 1);
    }
  } else {
    for (int i = t; i < cnt; i += 256) atomicAdd(&hist[ebufp[lo + i] >> 23], 1);
  }
  __syncthreads();
  const int h0 = hist[2 * t], h1 = hist[2 * t + 1];
  const int psum = h0 + h1;
  ts[t] = psum;
  __syncthreads();
  for (int off = 1; off < 256; off <<= 1) {
    int add = (t >= off) ? ts[t - off] : 0;
    __syncthreads();
    ts[t] += add;
    __syncthreads();
  }
  const int pexcl = ts[t] - psum;
  hist[2 * t] = lo + pexcl;
  hist[2 * t + 1] = lo + pexcl + h0;
  __syncthreads();
  const int nbase = b << 9;
  if (nbase + 2 * t < N) rowptr[nbase + 2 * t] = hist[2 * t];
  if (nbase + 2 * t + 1 < N) rowptr[nbase + 2 * t + 1] = hist[2 * t + 1];
  if (b == 0 && t == 0) rowptr[N] = E;
  __syncthreads();
  if (stage) {
    for (int i = t; i < cnt; i += 256) {
      unsigned int e = eb[i];
      int pos = atomicAdd(&hist[e >> 23], 1);
      csr[pos] = (int)(e & 0x7FFFFFu);
    }
  } else {
    for (int i = t; i < cnt; i += 256) {
      unsigned int e = ebufp[lo + i];
      int pos = atomicAdd(&hist[e >> 23], 1);
      csr[pos] = (int)(e & 0x7FFFFFu);
    }
  }
}

// ================= proj1: t1 = x @ w1_l (N x 32 @ 32 x 16) =================
__global__ __launch_bounds__(256) void proj1_kernel(const float* __restrict__ x,
                                                    const float* __restrict__ wl,
                                                    float* __restrict__ t1, int N) {
  __shared__ float w[32 * 16];
  const int t = threadIdx.x;
  if (t < 128) reinterpret_cast<float4*>(w)[t] = reinterpret_cast<const float4*>(wl)[t];
  __syncthreads();
  const int n = blockIdx.x * 256 + t;
  if (n >= N) return;
  float xr[32];
  const float4* xp = reinterpret_cast<const float4*>(x + (size_t)n * 32);
#pragma unroll
  for (int i = 0; i < 8; ++i) {
    float4 v = xp[i];
    xr[4 * i] = v.x; xr[4 * i + 1] = v.y; xr[4 * i + 2] = v.z; xr[4 * i + 3] = v.w;
  }
  float o[16];
#pragma unroll
  for (int j = 0; j < 16; ++j) o[j] = 0.f;
#pragma unroll
  for (int k = 0; k < 32; ++k) {
    float xv = xr[k];
#pragma unroll
    for (int j = 0; j < 16; ++j) o[j] = fmaf(xv, w[k * 16 + j], o[j]);
  }
  float4* op = reinterpret_cast<float4*>(t1 + (size_t)n * 16);
#pragma unroll
  for (int i = 0; i < 4; ++i) op[i] = make_float4(o[4 * i], o[4 * i + 1], o[4 * i + 2], o[4 * i + 3]);
}

// ================= linear1: out = mean(t1) + b1 + x @ w1_r =================
__global__ __launch_bounds__(256) void linear1_kernel(
    const int* __restrict__ rowptr, const int* __restrict__ csr,
    const float* __restrict__ t1, const float* __restrict__ x,
    const float* __restrict__ bias, const float* __restrict__ wr,
    float* __restrict__ out, float* __restrict__ bnsum_out, int N) {
  constexpr int K2P = 49;  // mean[16] | x[32] | pad
  __shared__ float As[64 * K2P];
  const int nb = blockIdx.x * 64;
  const int tid = threadIdx.x;

  {  // gather mean of t1: 4 threads/node, unroll 8
    const int nl = tid >> 2, t = tid & 3;
    const int n = nb + nl;
    float4 acc = make_float4(0.f, 0.f, 0.f, 0.f);
    float sc = 0.f;
    if (n < N) {
      const int r0 = rowptr[n], r1 = rowptr[n + 1];
      int p = r0;
      for (; p + 8 <= r1; p += 8) {
        int s[8];
#pragma unroll
        for (int u = 0; u < 8; ++u) s[u] = csr[p + u];
        float4 v[8];
#pragma unroll
        for (int u = 0; u < 8; ++u)
          v[u] = reinterpret_cast<const float4*>(t1 + (size_t)s[u] * 16)[t];
#pragma unroll
        for (int u = 0; u < 8; ++u) {
          acc.x += v[u].x; acc.y += v[u].y; acc.z += v[u].z; acc.w += v[u].w;
        }
      }
      for (; p < r1; ++p) {
        float4 v = reinterpret_cast<const float4*>(t1 + (size_t)csr[p] * 16)[t];
        acc.x += v.x; acc.y += v.y; acc.z += v.z; acc.w += v.w;
      }
      sc = 1.0f / fmaxf((float)(r1 - r0), 1.0f);
    }
    As[nl * K2P + t * 4 + 0] = acc.x * sc;
    As[nl * K2P + t * 4 + 1] = acc.y * sc;
    As[nl * K2P + t * 4 + 2] = acc.z * sc;
    As[nl * K2P + t * 4 + 3] = acc.w * sc;
  }

  {  // stage x rows
    for (int idx4 = tid; idx4 < 64 * 8; idx4 += 256) {
      int nl = idx4 >> 3, k4 = idx4 & 7;
      int n = nb + nl;
      float4 v = make_float4(0.f, 0.f, 0.f, 0.f);
      if (n < N) v = reinterpret_cast<const float4*>(x + (size_t)n * 32)[k4];
      As[nl * K2P + 16 + k4 * 4 + 0] = v.x;
      As[nl * K2P + 16 + k4 * 4 + 1] = v.y;
      As[nl * K2P + 16 + k4 * 4 + 2] = v.z;
      As[nl * K2P + 16 + k4 * 4 + 3] = v.w;
    }
  }
  __syncthreads();

  const int ty = tid >> 4, tx = tid & 15;
  float acc[4] = {0.f, 0.f, 0.f, 0.f};
  const float* A0 = &As[(ty * 4 + 0) * K2P + 16];
  const float* A1 = &As[(ty * 4 + 1) * K2P + 16];
  const float* A2 = &As[(ty * 4 + 2) * K2P + 16];
  const float* A3 = &As[(ty * 4 + 3) * K2P + 16];
#pragma unroll 4
  for (int k = 0; k < 32; ++k) {
    float w = wr[(size_t)k * 16 + tx];
    acc[0] = fmaf(A0[k], w, acc[0]);
    acc[1] = fmaf(A1[k], w, acc[1]);
    acc[2] = fmaf(A2[k], w, acc[2]);
    acc[3] = fmaf(A3[k], w, acc[3]);
  }

  const float bv = bias[tx];
  float s = 0.f, q = 0.f;
#pragma unroll
  for (int r = 0; r < 4; ++r) {
    int n = nb + ty * 4 + r;
    if (n < N) {
      float v = acc[r] + As[(ty * 4 + r) * K2P + tx] + bv;
      out[(size_t)n * 16 + tx] = v;
      s += v;
      q += v * v;
    }
  }

  __syncthreads();
  float* sL = As;
  float* qL = As + 16 * 16;
  sL[ty * 16 + tx] = s;
  qL[ty * 16 + tx] = q;
  __syncthreads();
  float* bn = bnsum_out + (size_t)(blockIdx.x & 7) * 32;
  if (tid < 16) {
    float ss = 0.f, qq = 0.f;
#pragma unroll
    for (int t = 0; t < 16; ++t) { ss += sL[t * 16 + tid]; qq += qL[t * 16 + tid]; }
    atomicAdd(&bn[tid], ss);
    atomicAdd(&bn[16 + tid], qq);
  }
}

// ================= prep2: h1b = bf16(relu(bn1(h1))); bn1 computed inline =============
__global__ __launch_bounds__(256) void prep2_kernel(const float* __restrict__ h1,
                                                    const float* __restrict__ bnsum1,
                                                    const float* __restrict__ g1,
                                                    const float* __restrict__ be1,
                                                    unsigned short* __restrict__ h1b,
                                                    float invN, int N) {
  __shared__ float ab[32];
  const int t = threadIdx.x;
  if (t < 16) {
    float m = 0.f, q = 0.f;
#pragma unroll
    for (int r = 0; r < 8; ++r) { m += bnsum1[r * 32 + t]; q += bnsum1[r * 32 + 16 + t]; }
    m *= invN;
    float var = q * invN - m * m;
    float a = g1[t] * rsqrtf(var + EPSF);
    ab[t] = a;
    ab[16 + t] = be1[t] - m * a;
  }
  __syncthreads();
  int n = blockIdx.x * 256 + t;
  if (n >= N) return;
  const float4* hp = reinterpret_cast<const float4*>(h1 + (size_t)n * 16);
  unsigned int o[8];
#pragma unroll
  for (int i = 0; i < 4; ++i) {
    float4 v = hp[i];
    const float4 A = *reinterpret_cast<const float4*>(&ab[i * 4]);
    const float4 B = *reinterpret_cast<const float4*>(&ab[16 + i * 4]);
    v = bnrelu4(v, A, B);
    o[2 * i] = f2bf(v.x) | (f2bf(v.y) << 16);
    o[2 * i + 1] = f2bf(v.z) | (f2bf(v.w) << 16);
  }
  uint4* op = reinterpret_cast<uint4*>(h1b + (size_t)n * 16);
  op[0] = make_uint4(o[0], o[1], o[2], o[3]);
  op[1] = make_uint4(o[4], o[5], o[6], o[7]);
}

// ================= linear2b: h2 = mean(h1b)@w2_l + b2 + h1b@w2_r (bf16 gather) ========
__global__ __launch_bounds__(256) void linear2b_kernel(
    const int* __restrict__ rowptr, const int* __restrict__ csr,
    const unsigned short* __restrict__ h1b, const float* __restrict__ wl,
    const float* __restrict__ bias, const float* __restrict__ wr,
    float* __restrict__ out, float* __restrict__ bnsum_out, int N) {
  constexpr int K2P = 33;  // mean[16] | root[16] | pad
  __shared__ float As[64 * K2P];
  const int nb = blockIdx.x * 64;
  const int tid = threadIdx.x;

  {  // gather: 4 threads/node, 8B (4 bf16) each, unroll 8
    const int nl = tid >> 2, t = tid & 3;
    const int n = nb + nl;
    float4 acc = make_float4(0.f, 0.f, 0.f, 0.f);
    float sc = 0.f;
    if (n < N) {
      const int r0 = rowptr[n], r1 = rowptr[n + 1];
      int p = r0;
      for (; p + 8 <= r1; p += 8) {
        int s[8];
#pragma unroll
        for (int u = 0; u < 8; ++u) s[u] = csr[p + u];
        uint2 v[8];
#pragma unroll
        for (int u = 0; u < 8; ++u)
          v[u] = *reinterpret_cast<const uint2*>(h1b + (size_t)s[u] * 16 + t * 4);
#pragma unroll
        for (int u = 0; u < 8; ++u) {
          acc.x += bf2f(v[u].x & 0xFFFFu);
          acc.y += bf2f(v[u].x >> 16);
          acc.z += bf2f(v[u].y & 0xFFFFu);
          acc.w += bf2f(v[u].y >> 16);
        }
      }
      for (; p < r1; ++p) {
        uint2 v = *reinterpret_cast<const uint2*>(h1b + (size_t)csr[p] * 16 + t * 4);
        acc.x += bf2f(v.x & 0xFFFFu);
        acc.y += bf2f(v.x >> 16);
        acc.z += bf2f(v.y & 0xFFFFu);
        acc.w += bf2f(v.y >> 16);
      }
      sc = 1.0f / fmaxf((float)(r1 - r0), 1.0f);
    }
    As[nl * K2P + t * 4 + 0] = acc.x * sc;
    As[nl * K2P + t * 4 + 1] = acc.y * sc;
    As[nl * K2P + t * 4 + 2] = acc.z * sc;
    As[nl * K2P + t * 4 + 3] = acc.w * sc;
  }

  // stage root rows (post-BN bf16 -> fp32)
  if (tid < 128) {
    int nl = tid >> 1, half = tid & 1;
    int n = nb + nl;
    uint4 u = make_uint4(0, 0, 0, 0);
    if (n < N) u = *reinterpret_cast<const uint4*>(h1b + (size_t)n * 16 + half * 8);
    float* d = &As[nl * K2P + 16 + half * 8];
    d[0] = bf2f(u.x & 0xFFFFu); d[1] = bf2f(u.x >> 16);
    d[2] = bf2f(u.y & 0xFFFFu); d[3] = bf2f(u.y >> 16);
    d[4] = bf2f(u.z & 0xFFFFu); d[5] = bf2f(u.z >> 16);
    d[6] = bf2f(u.w & 0xFFFFu); d[7] = bf2f(u.w >> 16);
  }
  __syncthreads();

  const int ty = tid >> 4, tx = tid & 15;
  const int j0 = tx * 4;
  float acc[4][4];
#pragma unroll
  for (int r = 0; r < 4; ++r)
#pragma unroll
    for (int c = 0; c < 4; ++c) acc[r][c] = 0.f;

  const float* A0 = &As[(ty * 4 + 0) * K2P];
  const float* A1 = &As[(ty * 4 + 1) * K2P];
  const float* A2 = &As[(ty * 4 + 2) * K2P];
  const float* A3 = &As[(ty * 4 + 3) * K2P];

#pragma unroll 4
  for (int k = 0; k < 16; ++k) {  // mean @ w2_l
    const float4 w = *reinterpret_cast<const float4*>(wl + (size_t)k * 64 + j0);
    const float wv[4] = {w.x, w.y, w.z, w.w};
    float a0 = A0[k], a1 = A1[k], a2 = A2[k], a3 = A3[k];
#pragma unroll
    for (int c = 0; c < 4; ++c) {
      acc[0][c] = fmaf(a0, wv[c], acc[0][c]);
      acc[1][c] = fmaf(a1, wv[c], acc[1][c]);
      acc[2][c] = fmaf(a2, wv[c], acc[2][c]);
      acc[3][c] = fmaf(a3, wv[c], acc[3][c]);
    }
  }
#pragma unroll 4
  for (int k = 0; k < 16; ++k) {  // root @ w2_r
    const float4 w = *reinterpret_cast<const float4*>(wr + (size_t)k * 64 + j0);
    const float wv[4] = {w.x, w.y, w.z, w.w};
    float a0 = A0[16 + k], a1 = A1[16 + k], a2 = A2[16 + k], a3 = A3[16 + k];
#pragma unroll
    for (int c = 0; c < 4; ++c) {
      acc[0][c] = fmaf(a0, wv[c], acc[0][c]);
      acc[1][c] = fmaf(a1, wv[c], acc[1][c]);
      acc[2][c] = fmaf(a2, wv[c], acc[2][c]);
      acc[3][c] = fmaf(a3, wv[c], acc[3][c]);
    }
  }

  float bv[4];
#pragma unroll
  for (int c = 0; c < 4; ++c) bv[c] = bias[j0 + c];

  float s[4], q[4];
#pragma unroll
  for (int c = 0; c < 4; ++c) { s[c] = 0.f; q[c] = 0.f; }
#pragma unroll
  for (int r = 0; r < 4; ++r) {
    int n = nb + ty * 4 + r;
    if (n < N) {
#pragma unroll
      for (int c = 0; c < 4; ++c) {
        float v = acc[r][c] + bv[c];
        out[(size_t)n * 64 + j0 + c] = v;
        s[c] += v;
        q[c] += v * v;
      }
    }
  }

  __syncthreads();
  float* sL = As;
  float* qL = As + 16 * 64;
#pragma unroll
  for (int c = 0; c < 4; ++c) {
    sL[ty * 64 + tx * 4 + c] = s[c];
    qL[ty * 64 + tx * 4 + c] = q[c];
  }
  __syncthreads();
  float* bn = bnsum_out + (size_t)(blockIdx.x & 7) * 128;
  for (int f = tid; f < 64; f += 256) {
    float ss = 0.f, qq = 0.f;
#pragma unroll
    for (int t = 0; t < 16; ++t) { ss += sL[t * 64 + f]; qq += qL[t * 64 + f]; }
    atomicAdd(&bn[f], ss);
    atomicAdd(&bn[64 + f], qq);
  }
}

// ================= prep3: bn2 inline; swizzled xh + row-major xlin ===================
__global__ __launch_bounds__(256) void prep3_kernel(const float* __restrict__ h2,
                                                    const float* __restrict__ bnsum2,
                                                    const float* __restrict__ g2,
                                                    const float* __restrict__ be2,
                                                    unsigned short* __restrict__ xh,
                                                    unsigned short* __restrict__ xlin,
                                                    float invN, int N) {
  __shared__ float ab[128];
  const int t = threadIdx.x;
  if (t < 64) {
    float m = 0.f, q = 0.f;
#pragma unroll
    for (int r = 0; r < 8; ++r) { m += bnsum2[r * 128 + t]; q += bnsum2[r * 128 + 64 + t]; }
    m *= invN;
    float var = q * invN - m * m;
    float a = g2[t] * rsqrtf(var + EPSF);
    ab[t] = a;
    ab[64 + t] = be2[t] - m * a;
  }
  __syncthreads();
  const int rg = t >> 7, ku = (t >> 4) & 7, r = t & 15;
  const int n = blockIdx.x * 32 + rg * 16 + r;
  if (n >= N) return;
  const float* hp = h2 + (size_t)n * 64 + ku * 8;
  const float4 v0 = *reinterpret_cast<const float4*>(hp);
  const float4 v1 = *reinterpret_cast<const float4*>(hp + 4);
  const float4 A0 = *reinterpret_cast<const float4*>(&ab[ku * 8]);
  const float4 A1 = *reinterpret_cast<const float4*>(&ab[ku * 8 + 4]);
  const float4 B0 = *reinterpret_cast<const float4*>(&ab[64 + ku * 8]);
  const float4 B1 = *reinterpret_cast<const float4*>(&ab[64 + ku * 8 + 4]);
  float rr[8];
  rr[0] = fmaxf(fmaf(v0.x, A0.x, B0.x), 0.f);
  rr[1] = fmaxf(fmaf(v0.y, A0.y, B0.y), 0.f);
  rr[2] = fmaxf(fmaf(v0.z, A0.z, B0.z), 0.f);
  rr[3] = fmaxf(fmaf(v0.w, A0.w, B0.w), 0.f);
  rr[4] = fmaxf(fmaf(v1.x, A1.x, B1.x), 0.f);
  rr[5] = fmaxf(fmaf(v1.y, A1.y, B1.y), 0.f);
  rr[6] = fmaxf(fmaf(v1.z, A1.z, B1.z), 0.f);
  rr[7] = fmaxf(fmaf(v1.w, A1.w, B1.w), 0.f);
  unsigned int uh[4];
#pragma unroll
  for (int j = 0; j < 4; ++j)
    uh[j] = f2bf(rr[2 * j]) | (f2bf(rr[2 * j + 1]) << 16);
  const size_t off = aswz(n, ku);
  *reinterpret_cast<uint4*>(xh + off) = make_uint4(uh[0], uh[1], uh[2], uh[3]);
  *reinterpret_cast<uint4*>(xlin + (size_t)n * 64 + ku * 8) =
      make_uint4(uh[0], uh[1], uh[2], uh[3]);
}

// ================= convw3: swizzled Bt (hi only) =================
__global__ __launch_bounds__(256) void convw3_kernel(const float* __restrict__ wl,
                                                     const float* __restrict__ wr,
                                                     unsigned short* __restrict__ bth) {
  int idx = blockIdx.x * 256 + threadIdx.x;
  if (idx >= 512 * 16) return;
  const int c = idx >> 4, ku = idx & 15;
  unsigned int uh[4];
#pragma unroll
  for (int jj = 0; jj < 4; ++jj) {
    unsigned int hh[2];
#pragma unroll
    for (int t = 0; t < 2; ++t) {
      int k = ku * 8 + jj * 2 + t;
      float w = (k < 64) ? wl[(size_t)k * 512 + c] : wr[(size_t)(k - 64) * 512 + c];
      hh[t] = f2bf(w);
    }
    uh[jj] = hh[0] | (hh[1] << 16);
  }
  const size_t off = ((size_t)(c >> 4) * 16 + ku) * 128 + (size_t)(c & 15) * 8;
  *reinterpret_cast<uint4*>(bth + off) = make_uint4(uh[0], uh[1], uh[2], uh[3]);
}

// ================= gather-mean: reads row-major xlin (x8 unrolled), swizzled mh ======
__global__ __launch_bounds__(256) void gather_mean_bf16(
    const unsigned short* __restrict__ xlin, const int* __restrict__ rowptr,
    const int* __restrict__ csr, unsigned short* __restrict__ mh, int N) {
  const int t = threadIdx.x;
  const int n = blockIdx.x * 32 + (t >> 3);
  const int ku = t & 7;
  if (n >= N) return;
  float acc[8];
#pragma unroll
  for (int i = 0; i < 8; ++i) acc[i] = 0.f;
  const int r0 = rowptr[n], r1 = rowptr[n + 1];
  int p = r0;
  for (; p + 8 <= r1; p += 8) {
    int s[8];
#pragma unroll
    for (int u = 0; u < 8; ++u) s[u] = csr[p + u];
    uint4 u4[8];
#pragma unroll
    for (int u = 0; u < 8; ++u)
      u4[u] = *reinterpret_cast<const uint4*>(xlin + (size_t)s[u] * 64 + ku * 8);
#pragma unroll
    for (int u = 0; u < 8; ++u) {
      const unsigned int uu[4] = {u4[u].x, u4[u].y, u4[u].z, u4[u].w};
#pragma unroll
      for (int j = 0; j < 4; ++j) {
        acc[2 * j]     += bf2f(uu[j] & 0xFFFFu);
        acc[2 * j + 1] += bf2f(uu[j] >> 16);
      }
    }
  }
  for (; p < r1; ++p) {
    const int s = csr[p];
    const uint4 u = *reinterpret_cast<const uint4*>(xlin + (size_t)s * 64 + ku * 8);
    const unsigned int uu[4] = {u.x, u.y, u.z, u.w};
#pragma unroll
    for (int j = 0; j < 4; ++j) {
      acc[2 * j]     += bf2f(uu[j] & 0xFFFFu);
      acc[2 * j + 1] += bf2f(uu[j] >> 16);
    }
  }
  const float sc = 1.0f / fmaxf((float)(r1 - r0), 1.0f);
  unsigned int oh[4];
#pragma unroll
  for (int j = 0; j < 4; ++j)
    oh[j] = f2bf(acc[2 * j] * sc) | (f2bf(acc[2 * j + 1] * sc) << 16);
  const size_t off = aswz(n, ku);
  *reinterpret_cast<uint4*>(mh + off) = make_uint4(oh[0], oh[1], oh[2], oh[3]);
}

// ================= layer-3 MFMA GEMM: 2 row-tiles/block, merged epilogue ============
// 128 rows x 256 cols per block; stats/pool merged across tiles -> atomics halved.
__global__ __launch_bounds__(256, 2) void mfma3_kernel(
    const unsigned short* __restrict__ mh, const unsigned short* __restrict__ xh,
    const unsigned short* __restrict__ bth, const float* __restrict__ bias,
    const int* __restrict__ batchp, float* __restrict__ bnsum,
    unsigned int* __restrict__ pmax, unsigned int* __restrict__ pmin, int N) {
  __shared__ int gb[128];
  const int tid = threadIdx.x;
  const int nb = blockIdx.x * 128;
  const int colbase = blockIdx.y * 256;
  if (tid < 128) gb[tid] = (nb + tid < N) ? batchp[nb + tid] : 0x7FFFFFFF;
  __syncthreads();

  const int wid = tid >> 6, lane = tid & 63;
  const int l16 = lane & 15, lg = lane >> 4;
  const int wcol = colbase + wid * 64;

  const int bbase = (wcol >> 4) * 2048 + lg * 128 + l16 * 8;

  float* bn = bnsum + (size_t)(blockIdx.x & 7) * 1024;
  const bool full = (nb + 128 <= N);
  const bool uni = full && (gb[0] == gb[127]);
  const int g0 = gb[0];

  // carried stats (merged across row-tiles)
  float sA[4], qA[4], mxA[4], mnA[4];
#pragma unroll
  for (int c = 0; c < 4; ++c) { sA[c] = 0.f; qA[c] = 0.f; mxA[c] = -INFINITY; mnA[c] = INFINITY; }

#pragma unroll
  for (int rt = 0; rt < 2; ++rt) {
    const int abase = (blockIdx.x * 8 + rt * 4) * 1024 + lg * 128 + l16 * 8;

    short8 ah[4][4];
#pragma unroll
    for (int rb = 0; rb < 4; ++rb) {
      ah[0][rb] = *reinterpret_cast<const short8*>(mh + abase + rb * 1024);
      ah[1][rb] = *reinterpret_cast<const short8*>(mh + abase + 512 + rb * 1024);
      ah[2][rb] = *reinterpret_cast<const short8*>(xh + abase + rb * 1024);
      ah[3][rb] = *reinterpret_cast<const short8*>(xh + abase + 512 + rb * 1024);
    }

    f32x4 acc[4][4];
#pragma unroll
    for (int rb = 0; rb < 4; ++rb)
#pragma unroll
      for (int cb = 0; cb < 4; ++cb) acc[rb][cb] = (f32x4){0.f, 0.f, 0.f, 0.f};

#pragma unroll
    for (int ks = 0; ks < 4; ++ks) {
#pragma unroll
      for (int cb = 0; cb < 4; ++cb) {
        const short8 bh = *reinterpret_cast<const short8*>(bth + bbase + cb * 2048 + ks * 512);
#pragma unroll
        for (int rb = 0; rb < 4; ++rb) {
          acc[rb][cb] = __builtin_amdgcn_mfma_f32_16x16x32_bf16(ah[ks][rb], bh, acc[rb][cb], 0, 0, 0);
        }
      }
    }

    if (full) {
#pragma unroll
      for (int cb = 0; cb < 4; ++cb) {
        float s0 = 0.f, q0 = 0.f, mx0 = -INFINITY, mn0 = INFINITY;
#pragma unroll
        for (int rb = 0; rb < 4; ++rb)
#pragma unroll
          for (int r = 0; r < 4; ++r) {
            const float a = acc[rb][cb][r];
            s0 += a;
            q0 = fmaf(a, a, q0);
            mx0 = fmaxf(mx0, a);
            mn0 = fminf(mn0, a);
          }
        sA[cb] += s0;
        qA[cb] += q0;
        mxA[cb] = fmaxf(mxA[cb], mx0);
        mnA[cb] = fminf(mnA[cb], mn0);
      }
      if (!uni) {  // segmented pool per tile (rare boundary blocks)
#pragma unroll
        for (int cb = 0; cb < 4; ++cb) {
          const int col = wcol + cb * 16 + l16;
          const float bv = bias[col];
          int curg = -1;
          float rmx = -INFINITY, rmn = INFINITY;
#pragma unroll
          for (int rb = 0; rb < 4; ++rb)
#pragma unroll
            for (int r = 0; r < 4; ++r) {
              const int row = rt * 64 + rb * 16 + lg * 4 + r;
              const int g = gb[row];
              if (g != curg) {
                if (curg >= 0) {
                  atomicMax(&pmax[(size_t)curg * 512 + col], enc_key(rmx + bv));
                  atomicMin(&pmin[(size_t)curg * 512 + col], enc_key(rmn + bv));
                }
                curg = g; rmx = -INFINITY; rmn = INFINITY;
              }
              const float a = acc[rb][cb][r];
              rmx = fmaxf(rmx, a); rmn = fminf(rmn, a);
            }
          if (curg >= 0) {
            atomicMax(&pmax[(size_t)curg * 512 + col], enc_key(rmx + bv));
            atomicMin(&pmin[(size_t)curg * 512 + col], enc_key(rmn + bv));
          }
        }
      }
    } else {
      // tail block: masked per-element path for this tile
      const int nbt = nb + rt * 64;
#pragma unroll
      for (int cb = 0; cb < 4; ++cb) {
        const int col = wcol + cb * 16 + l16;
        const float bv = bias[col];
        float s = 0.f, q = 0.f;
#pragma unroll
        for (int rb = 0; rb < 4; ++rb)
#pragma unroll
          for (int r = 0; r < 4; ++r) {
            const int row = rb * 16 + lg * 4 + r;
            float v = acc[rb][cb][r] + bv;
            acc[rb][cb][r] = v;
            if (nbt + row < N) {
              s += v; q += v * v;
            }
          }
        s += __shfl_xor(s, 16); s += __shfl_xor(s, 32);
        q += __shfl_xor(q, 16); q += __shfl_xor(q, 32);
        if (lane < 16) {
          atomicAdd(&bn[col], s);
          atomicAdd(&bn[512 + col], q);
        }
        int curg = -1;
        float rmx = -INFINITY, rmn = INFINITY;
#pragma unroll
        for (int rb = 0; rb < 4; ++rb)
#pragma unroll
          for (int r = 0; r < 4; ++r) {
            const int row = rt * 64 + rb * 16 + lg * 4 + r;
            const int g = gb[row];
            if (g != curg) {
              if (curg >= 0 && curg != 0x7FFFFFFF) {
                atomicMax(&pmax[(size_t)curg * 512 + col], enc_key(rmx));
                atomicMin(&pmin[(size_t)curg * 512 + col], enc_key(rmn));
              }
              curg = g; rmx = -INFINITY; rmn = INFINITY;
            }
            if (g != 0x7FFFFFFF) {
              const float v = acc[rb][cb][r];
              rmx = fmaxf(rmx, v); rmn = fminf(rmn, v);
            }
          }
        if (curg >= 0 && curg != 0x7FFFFFFF) {
          atomicMax(&pmax[(size_t)curg * 512 + col], enc_key(rmx));
          atomicMin(&pmin[(size_t)curg * 512 + col], enc_key(rmn));
        }
      }
    }
  }

  if (full) {
#pragma unroll
    for (int cb = 0; cb < 4; ++cb) {
      const int col = wcol + cb * 16 + l16;
      const float bv = bias[col];
      float s0 = sA[cb], q0 = qA[cb];
      s0 += __shfl_xor(s0, 16); s0 += __shfl_xor(s0, 32);
      q0 += __shfl_xor(q0, 16); q0 += __shfl_xor(q0, 32);
      if (lane < 16) {
        // 128 rows: s = s0 + 128*bv ; q = q0 + 2*bv*s0 + 128*bv^2
        atomicAdd(&bn[col], fmaf(128.f, bv, s0));
        atomicAdd(&bn[512 + col], q0 + 2.f * bv * s0 + 128.f * bv * bv);
      }
      if (uni) {
        float mx0 = mxA[cb], mn0 = mnA[cb];
        mx0 = fmaxf(mx0, __shfl_xor(mx0, 16)); mx0 = fmaxf(mx0, __shfl_xor(mx0, 32));
        mn0 = fminf(mn0, __shfl_xor(mn0, 16)); mn0 = fminf(mn0, __shfl_xor(mn0, 32));
        if (lane < 16) {
          atomicMax(&pmax[(size_t)g0 * 512 + col], enc_key(mx0 + bv));
          atomicMin(&pmin[(size_t)g0 * 512 + col], enc_key(mn0 + bv));
        }
      }
    }
  }
}

// ================= MLP head (bn3 inline; decodes pooled keys, BN3+ReLU) ==============
__global__ __launch_bounds__(256) void head_kernel(const unsigned int* __restrict__ pmax,
                                                   const unsigned int* __restrict__ pmin,
                                                   const float* __restrict__ bnsum3,
                                                   const float* __restrict__ g3,
                                                   const float* __restrict__ be3,
                                                   const float* __restrict__ w1,
                                                   const float* __restrict__ b1,
                                                   const float* __restrict__ w2,
                                                   const float* __restrict__ b2,
                                                   float* __restrict__ out, float invN) {
  __shared__ float pr[512];
  __shared__ float hid[256];
  int g = blockIdx.x;
  int t = threadIdx.x;
  for (int i = t; i < 512; i += 256) {
    float m = 0.f, q = 0.f;
#pragma unroll
    for (int r = 0; r < 8; ++r) { m += bnsum3[r * 1024 + i]; q += bnsum3[r * 1024 + 512 + i]; }
    m *= invN;
    float var = q * invN - m * m;
    float a = g3[i] * rsqrtf(var + EPSF);
    float b = be3[i] - m * a;
    float v = (a >= 0.f) ? dec_key(pmax[(size_t)g * 512 + i])
                         : dec_key(pmin[(size_t)g * 512 + i]);
    pr[i] = fmaxf(fmaf(v, a, b), 0.f);
  }
  __syncthreads();
  float acc = b1[t];
  for (int i = 0; i < 512; ++i) acc = fmaf(pr[i], w1[(size_t)i * 256 + t], acc);
  hid[t] = fmaxf(acc, 0.f);
  __syncthreads();
  if (t < 10) {
    float o = b2[t];
    for (int j = 0; j < 256; ++j) o = fmaf(hid[j], w2[(size_t)j * 10 + t], o);
    out[(size_t)g * 10 + t] = o;
  }
}

extern "C" void kernel_launch(void* const* d_in, const int* in_sizes, int n_in,
                              void* d_out, int out_size, void* d_ws, size_t ws_size,
                              hipStream_t stream) {
  const float* x    = (const float*)d_in[0];
  const int*   ei   = (const int*)d_in[1];
  const int*   batch= (const int*)d_in[2];
  const float* w1_l = (const float*)d_in[3];
  const float* b1   = (const float*)d_in[4];
  const float* w1_r = (const float*)d_in[5];
  const float* w2_l = (const float*)d_in[6];
  const float* b2   = (const float*)d_in[7];
  const float* w2_r = (const float*)d_in[8];
  const float* w3_l = (const float*)d_in[9];
  const float* b3   = (const float*)d_in[10];
  const float* w3_r = (const float*)d_in[11];
  const float* g1   = (const float*)d_in[12];
  const float* be1  = (const float*)d_in[13];
  const float* g2   = (const float*)d_in[14];
  const float* be2  = (const float*)d_in[15];
  const float* g3   = (const float*)d_in[16];
  const float* be3  = (const float*)d_in[17];
  const float* wl1  = (const float*)d_in[18];
  const float* bl1  = (const float*)d_in[19];
  const float* wl2  = (const float*)d_in[20];
  const float* bl2  = (const float*)d_in[21];

  const int N = in_sizes[0] / 32;
  const int E = in_sizes[1] / 2;
  const int* src  = ei;
  const int* dstp = ei + E;
  float* outp = (float*)d_out;

  const int gx128 = (N + 127) / 128;    // mfma3 row blocks (128 rows each)
  const int Npad = gx128 * 128;         // padded rows for swizzled planes
  const int nbuck = (N + 511) >> 9;     // <=256 for N<=131072

  size_t off = 0;
  auto alloc = [&](size_t bytes) -> void* {
    void* p = (char*)d_ws + off;
    off += (bytes + 255) & ~(size_t)255;
    return p;
  };
  int*   rowptr = (int*)alloc(((size_t)N + 1) * 4);
  int*   csr    = (int*)alloc((size_t)E * 4);
  int*   bcnt   = (int*)alloc(256 * 4);
  int*   bbase  = (int*)alloc(257 * 4);
  int*   bcur   = (int*)alloc(256 * 4);
  unsigned int* ebuf = (unsigned int*)alloc((size_t)E * 4);
  float* t1     = (float*)alloc((size_t)N * 16 * 4);
  float* h1     = (float*)alloc((size_t)N * 16 * 4);
  unsigned short* h1b = (unsigned short*)alloc((size_t)N * 16 * 2);
  float* h2     = (float*)alloc((size_t)N * 64 * 4);
  unsigned short* xh = (unsigned short*)alloc((size_t)Npad * 64 * 2);
  unsigned short* mh = (unsigned short*)alloc((size_t)Npad * 64 * 2);
  unsigned short* xlin = (unsigned short*)alloc((size_t)N * 64 * 2);
  unsigned short* bth = (unsigned short*)alloc(512 * 128 * 2);
  float* bnsum1 = (float*)alloc(8 * 32 * 4);
  float* bnsum2 = (float*)alloc(8 * 128 * 4);
  float* bnsum3 = (float*)alloc(8 * 1024 * 4);
  unsigned int* pmax = (unsigned int*)alloc((size_t)NUM_GRAPHS * 512 * 4);
  unsigned int* pmin = (unsigned int*)alloc((size_t)NUM_GRAPHS * 512 * 4);
  (void)ws_size;

  const float invN = 1.0f / (float)N;

  // ---------- consolidated init (bcnt, bnsums, pooled keys) ----------
  init_kernel<<<(NUM_GRAPHS * 512 + 255) / 256, 256, 0, stream>>>(
      bcnt, bnsum1, bnsum2, bnsum3, pmax, pmin);

  // ---------- CSR build: bhist -> bscan -> bucketA(packed) -> bucketCSR ----------
  bhist_kernel<<<(E + 8191) / 8192, 256, 0, stream>>>(dstp, bcnt, E);
  bscan_kernel<<<1, 256, 0, stream>>>(bcnt, bbase, bcur, E);
  bucketA_kernel<<<(E + 8191) / 8192, 256, 0, stream>>>(src, dstp, bcur, ebuf, E);
  bucketCSR_kernel<<<nbuck, 256, 0, stream>>>(ebuf, bbase, rowptr, csr, N, E);

  convw3_kernel<<<(512 * 16 + 255) / 256, 256, 0, stream>>>(w3_l, w3_r, bth);

  // zero the pad rows of the swizzled planes (contiguous tail when N%16==0)
  if (Npad > N && (N & 15) == 0) {
    const size_t padBytes = (size_t)(Npad - N) * 64 * 2;
    hipMemsetAsync(xh + (size_t)N * 64, 0, padBytes, stream);
    hipMemsetAsync(mh + (size_t)N * 64, 0, padBytes, stream);
  }

  // ---------- layer 1: 32 -> 16 (pre-projected mean) ----------
  proj1_kernel<<<(N + 255) / 256, 256, 0, stream>>>(x, w1_l, t1, N);
  linear1_kernel<<<(N + 63) / 64, 256, 0, stream>>>(
      rowptr, csr, t1, x, b1, w1_r, h1, bnsum1, N);

  // ---------- layer 2: 16 -> 64 (bn1 inline in prep2; bf16 gather) ----------
  prep2_kernel<<<(N + 255) / 256, 256, 0, stream>>>(h1, bnsum1, g1, be1, h1b, invN, N);
  linear2b_kernel<<<(N + 63) / 64, 256, 0, stream>>>(
      rowptr, csr, h1b, w2_l, b2, w2_r, h2, bnsum2, N);

  // ---------- layer 3: 64 -> 512 via MFMA (bn2 inline in prep3) ----------
  prep3_kernel<<<(N + 31) / 32, 256, 0, stream>>>(h2, bnsum2, g2, be2, xh, xlin, invN, N);
  gather_mean_bf16<<<(N + 31) / 32, 256, 0, stream>>>(xlin, rowptr, csr, mh, N);
  mfma3_kernel<<<dim3(gx128, 2), 256, 0, stream>>>(
      mh, xh, bth, b3, batch, bnsum3, pmax, pmin, N);

  // ---------- head (bn3 inline) ----------
  head_kernel<<<NUM_GRAPHS, 256, 0, stream>>>(
      pmax, pmin, bnsum3, g3, be3, wl1, bl1, wl2, bl2, outp, invN);
}

// Round 19
// 242.913 us; speedup vs baseline: 1.1391x; 1.1391x over previous
//
#include <hip/hip_runtime.h>
#include <hip/hip_bf16.h>
#include <cstdint>

#define NUM_GRAPHS 128
constexpr float EPSF = 1e-5f;

using short8 = __attribute__((ext_vector_type(8))) short;
using f32x4  = __attribute__((ext_vector_type(4))) float;

// order-preserving float<->uint key (works for negatives)
__device__ __forceinline__ unsigned int enc_key(float f) {
  unsigned int b = __float_as_uint(f);
  return (b & 0x80000000u) ? ~b : (b | 0x80000000u);
}
__device__ __forceinline__ float dec_key(unsigned int k) {
  return __uint_as_float((k & 0x80000000u) ? (k ^ 0x80000000u) : ~k);
}

// manual bf16 RNE conversion (finite values)
__device__ __forceinline__ unsigned int f2bf(float v) {
  unsigned int u = __float_as_uint(v);
  u += 0x7FFFu + ((u >> 16) & 1u);
  return (u >> 16) & 0xFFFFu;
}
__device__ __forceinline__ float bf2f(unsigned int h) {
  return __uint_as_float(h << 16);
}

// swizzled A-plane offset (plane = N x 64 bf16):
//   off(n, f) = (n>>4)*1024 + (f>>3)*128 + (n&15)*8 + (f&7)
__device__ __forceinline__ size_t aswz(int n, int kunit) {
  return ((size_t)(n >> 4) * 8 + kunit) * 128 + (size_t)(n & 15) * 8;
}

__device__ __forceinline__ float4 bnrelu4(float4 v, const float4 A, const float4 B) {
  v.x = fmaxf(fmaf(v.x, A.x, B.x), 0.f);
  v.y = fmaxf(fmaf(v.y, A.y, B.y), 0.f);
  v.z = fmaxf(fmaf(v.z, A.z, B.z), 0.f);
  v.w = fmaxf(fmaf(v.w, A.w, B.w), 0.f);
  return v;
}

// ================= consolidated init: bcnt=0, bnsums=0, pooled keys ==================
__global__ __launch_bounds__(256) void init_kernel(int* __restrict__ bcnt,
                                                   float* __restrict__ bnsum1,
                                                   float* __restrict__ bnsum2,
                                                   float* __restrict__ bnsum3,
                                                   unsigned int* __restrict__ pmax,
                                                   unsigned int* __restrict__ pmin) {
  const int i = blockIdx.x * 256 + threadIdx.x;  // grid covers 65536
  if (i < 256) bcnt[i] = 0;
  if (i < 8 * 32) bnsum1[i] = 0.f;
  if (i < 8 * 128) bnsum2[i] = 0.f;
  if (i < 8 * 1024) bnsum3[i] = 0.f;
  if (i < NUM_GRAPHS * 512) {
    pmax[i] = 0x007FFFFFu;
    pmin[i] = 0xFF800000u;
  }
}

// ================= CSR build (bucketed; bucket = dst>>9, <=256 buckets) =================

__global__ __launch_bounds__(256) void bhist_kernel(const int* __restrict__ dst,
                                                    int* __restrict__ bcnt, int E) {
  __shared__ int hist[256];
  const int t = threadIdx.x;
  const int e0 = blockIdx.x * 8192;
  const int e1 = min(e0 + 8192, E);
  hist[t] = 0;
  __syncthreads();
  for (int e = e0 + t; e < e1; e += 256) atomicAdd(&hist[dst[e] >> 9], 1);
  __syncthreads();
  if (hist[t]) atomicAdd(&bcnt[t], hist[t]);
}

__global__ void bscan_kernel(const int* __restrict__ bcnt, int* __restrict__ bbase,
                             int* __restrict__ bcur, int E) {
  __shared__ int ts[256];
  const int t = threadIdx.x;
  int v = bcnt[t];
  ts[t] = v;
  __syncthreads();
  for (int off = 1; off < 256; off <<= 1) {
    int add = (t >= off) ? ts[t - off] : 0;
    __syncthreads();
    ts[t] += add;
    __syncthreads();
  }
  int excl = ts[t] - v;
  bbase[t] = excl;
  bcur[t] = excl;
  if (t == 255) bbase[256] = E;
}

// pass A: chunk edges, LDS-histogram by bucket, reserve, write packed src|(localdst<<23)
__global__ __launch_bounds__(256) void bucketA_kernel(const int* __restrict__ src,
                                                      const int* __restrict__ dst,
                                                      int* __restrict__ bcur,
                                                      unsigned int* __restrict__ ebuf, int E) {
  __shared__ int hist[256];
  __shared__ int base[256];
  const int t = threadIdx.x;
  const int e0 = blockIdx.x * 8192;
  const int e1 = min(e0 + 8192, E);
  hist[t] = 0;
  __syncthreads();
  for (int e = e0 + t; e < e1; e += 256) atomicAdd(&hist[dst[e] >> 9], 1);
  __syncthreads();
  int c = hist[t];
  base[t] = c ? atomicAdd(&bcur[t], c) : 0;
  hist[t] = 0;
  __syncthreads();
  for (int e = e0 + t; e < e1; e += 256) {
    int d = dst[e];
    int b = d >> 9;
    int p = base[b] + atomicAdd(&hist[b], 1);
    ebuf[p] = (unsigned int)src[e] | ((unsigned int)(d & 511) << 23);
  }
}

// one block per bucket: LDS-stage edges, histogram+scan -> rowptr slice, scatter csr.
__global__ __launch_bounds__(256) void bucketCSR_kernel(
    const unsigned int* __restrict__ ebufp, const int* __restrict__ bbase,
    int* __restrict__ rowptr, int* __restrict__ csr, int N, int E) {
  __shared__ unsigned int eb[12288];
  __shared__ int hist[512];
  __shared__ int ts[256];
  const int b = blockIdx.x;
  const int t = threadIdx.x;
  const int lo = bbase[b], hi = bbase[b + 1];
  const int cnt = hi - lo;
  const bool stage = (cnt <= 12288);
  hist[t] = 0;
  hist[t + 256] = 0;
  __syncthreads();
  if (stage) {
    for (int i = t; i < cnt; i += 256) {
      unsigned int e = ebufp[lo + i];
      eb[i] = e;
      atomicAdd(&hist[e >> 23], 1);
    }
  } else {
    for (int i = t; i < cnt; i += 256) atomicAdd(&hist[ebufp[lo + i] >> 23], 1);
  }
  __syncthreads();
  const int h0 = hist[2 * t], h1 = hist[2 * t + 1];
  const int psum = h0 + h1;
  ts[t] = psum;
  __syncthreads();
  for (int off = 1; off < 256; off <<= 1) {
    int add = (t >= off) ? ts[t - off] : 0;
    __syncthreads();
    ts[t] += add;
    __syncthreads();
  }
  const int pexcl = ts[t] - psum;
  hist[2 * t] = lo + pexcl;
  hist[2 * t + 1] = lo + pexcl + h0;
  __syncthreads();
  const int nbase = b << 9;
  if (nbase + 2 * t < N) rowptr[nbase + 2 * t] = hist[2 * t];
  if (nbase + 2 * t + 1 < N) rowptr[nbase + 2 * t + 1] = hist[2 * t + 1];
  if (b == 0 && t == 0) rowptr[N] = E;
  __syncthreads();
  if (stage) {
    for (int i = t; i < cnt; i += 256) {
      unsigned int e = eb[i];
      int pos = atomicAdd(&hist[e >> 23], 1);
      csr[pos] = (int)(e & 0x7FFFFFu);
    }
  } else {
    for (int i = t; i < cnt; i += 256) {
      unsigned int e = ebufp[lo + i];
      int pos = atomicAdd(&hist[e >> 23], 1);
      csr[pos] = (int)(e & 0x7FFFFFu);
    }
  }
}

// ================= proj1: t1 = x @ w1_l (N x 32 @ 32 x 16) =================
__global__ __launch_bounds__(256) void proj1_kernel(const float* __restrict__ x,
                                                    const float* __restrict__ wl,
                                                    float* __restrict__ t1, int N) {
  __shared__ float w[32 * 16];
  const int t = threadIdx.x;
  if (t < 128) reinterpret_cast<float4*>(w)[t] = reinterpret_cast<const float4*>(wl)[t];
  __syncthreads();
  const int n = blockIdx.x * 256 + t;
  if (n >= N) return;
  float xr[32];
  const float4* xp = reinterpret_cast<const float4*>(x + (size_t)n * 32);
#pragma unroll
  for (int i = 0; i < 8; ++i) {
    float4 v = xp[i];
    xr[4 * i] = v.x; xr[4 * i + 1] = v.y; xr[4 * i + 2] = v.z; xr[4 * i + 3] = v.w;
  }
  float o[16];
#pragma unroll
  for (int j = 0; j < 16; ++j) o[j] = 0.f;
#pragma unroll
  for (int k = 0; k < 32; ++k) {
    float xv = xr[k];
#pragma unroll
    for (int j = 0; j < 16; ++j) o[j] = fmaf(xv, w[k * 16 + j], o[j]);
  }
  float4* op = reinterpret_cast<float4*>(t1 + (size_t)n * 16);
#pragma unroll
  for (int i = 0; i < 4; ++i) op[i] = make_float4(o[4 * i], o[4 * i + 1], o[4 * i + 2], o[4 * i + 3]);
}

// ================= linear1: out = mean(t1) + b1 + x @ w1_r =================
__global__ __launch_bounds__(256) void linear1_kernel(
    const int* __restrict__ rowptr, const int* __restrict__ csr,
    const float* __restrict__ t1, const float* __restrict__ x,
    const float* __restrict__ bias, const float* __restrict__ wr,
    float* __restrict__ out, float* __restrict__ bnsum_out, int N) {
  constexpr int K2P = 49;  // mean[16] | x[32] | pad
  __shared__ float As[64 * K2P];
  const int nb = blockIdx.x * 64;
  const int tid = threadIdx.x;

  {  // gather mean of t1: 4 threads/node, unroll 8
    const int nl = tid >> 2, t = tid & 3;
    const int n = nb + nl;
    float4 acc = make_float4(0.f, 0.f, 0.f, 0.f);
    float sc = 0.f;
    if (n < N) {
      const int r0 = rowptr[n], r1 = rowptr[n + 1];
      int p = r0;
      for (; p + 8 <= r1; p += 8) {
        int s[8];
#pragma unroll
        for (int u = 0; u < 8; ++u) s[u] = csr[p + u];
        float4 v[8];
#pragma unroll
        for (int u = 0; u < 8; ++u)
          v[u] = reinterpret_cast<const float4*>(t1 + (size_t)s[u] * 16)[t];
#pragma unroll
        for (int u = 0; u < 8; ++u) {
          acc.x += v[u].x; acc.y += v[u].y; acc.z += v[u].z; acc.w += v[u].w;
        }
      }
      for (; p < r1; ++p) {
        float4 v = reinterpret_cast<const float4*>(t1 + (size_t)csr[p] * 16)[t];
        acc.x += v.x; acc.y += v.y; acc.z += v.z; acc.w += v.w;
      }
      sc = 1.0f / fmaxf((float)(r1 - r0), 1.0f);
    }
    As[nl * K2P + t * 4 + 0] = acc.x * sc;
    As[nl * K2P + t * 4 + 1] = acc.y * sc;
    As[nl * K2P + t * 4 + 2] = acc.z * sc;
    As[nl * K2P + t * 4 + 3] = acc.w * sc;
  }

  {  // stage x rows
    for (int idx4 = tid; idx4 < 64 * 8; idx4 += 256) {
      int nl = idx4 >> 3, k4 = idx4 & 7;
      int n = nb + nl;
      float4 v = make_float4(0.f, 0.f, 0.f, 0.f);
      if (n < N) v = reinterpret_cast<const float4*>(x + (size_t)n * 32)[k4];
      As[nl * K2P + 16 + k4 * 4 + 0] = v.x;
      As[nl * K2P + 16 + k4 * 4 + 1] = v.y;
      As[nl * K2P + 16 + k4 * 4 + 2] = v.z;
      As[nl * K2P + 16 + k4 * 4 + 3] = v.w;
    }
  }
  __syncthreads();

  const int ty = tid >> 4, tx = tid & 15;
  float acc[4] = {0.f, 0.f, 0.f, 0.f};
  const float* A0 = &As[(ty * 4 + 0) * K2P + 16];
  const float* A1 = &As[(ty * 4 + 1) * K2P + 16];
  const float* A2 = &As[(ty * 4 + 2) * K2P + 16];
  const float* A3 = &As[(ty * 4 + 3) * K2P + 16];
#pragma unroll 4
  for (int k = 0; k < 32; ++k) {
    float w = wr[(size_t)k * 16 + tx];
    acc[0] = fmaf(A0[k], w, acc[0]);
    acc[1] = fmaf(A1[k], w, acc[1]);
    acc[2] = fmaf(A2[k], w, acc[2]);
    acc[3] = fmaf(A3[k], w, acc[3]);
  }

  const float bv = bias[tx];
  float s = 0.f, q = 0.f;
#pragma unroll
  for (int r = 0; r < 4; ++r) {
    int n = nb + ty * 4 + r;
    if (n < N) {
      float v = acc[r] + As[(ty * 4 + r) * K2P + tx] + bv;
      out[(size_t)n * 16 + tx] = v;
      s += v;
      q += v * v;
    }
  }

  __syncthreads();
  float* sL = As;
  float* qL = As + 16 * 16;
  sL[ty * 16 + tx] = s;
  qL[ty * 16 + tx] = q;
  __syncthreads();
  float* bn = bnsum_out + (size_t)(blockIdx.x & 7) * 32;
  if (tid < 16) {
    float ss = 0.f, qq = 0.f;
#pragma unroll
    for (int t = 0; t < 16; ++t) { ss += sL[t * 16 + tid]; qq += qL[t * 16 + tid]; }
    atomicAdd(&bn[tid], ss);
    atomicAdd(&bn[16 + tid], qq);
  }
}

// ================= prep2: h1b = bf16(relu(bn1(h1))); bn1 computed inline =============
__global__ __launch_bounds__(256) void prep2_kernel(const float* __restrict__ h1,
                                                    const float* __restrict__ bnsum1,
                                                    const float* __restrict__ g1,
                                                    const float* __restrict__ be1,
                                                    unsigned short* __restrict__ h1b,
                                                    float invN, int N) {
  __shared__ float ab[32];
  const int t = threadIdx.x;
  if (t < 16) {
    float m = 0.f, q = 0.f;
#pragma unroll
    for (int r = 0; r < 8; ++r) { m += bnsum1[r * 32 + t]; q += bnsum1[r * 32 + 16 + t]; }
    m *= invN;
    float var = q * invN - m * m;
    float a = g1[t] * rsqrtf(var + EPSF);
    ab[t] = a;
    ab[16 + t] = be1[t] - m * a;
  }
  __syncthreads();
  int n = blockIdx.x * 256 + t;
  if (n >= N) return;
  const float4* hp = reinterpret_cast<const float4*>(h1 + (size_t)n * 16);
  unsigned int o[8];
#pragma unroll
  for (int i = 0; i < 4; ++i) {
    float4 v = hp[i];
    const float4 A = *reinterpret_cast<const float4*>(&ab[i * 4]);
    const float4 B = *reinterpret_cast<const float4*>(&ab[16 + i * 4]);
    v = bnrelu4(v, A, B);
    o[2 * i] = f2bf(v.x) | (f2bf(v.y) << 16);
    o[2 * i + 1] = f2bf(v.z) | (f2bf(v.w) << 16);
  }
  uint4* op = reinterpret_cast<uint4*>(h1b + (size_t)n * 16);
  op[0] = make_uint4(o[0], o[1], o[2], o[3]);
  op[1] = make_uint4(o[4], o[5], o[6], o[7]);
}

// ================= linear2b: h2 = mean(h1b)@w2_l + b2 + h1b@w2_r (bf16 gather) ========
__global__ __launch_bounds__(256) void linear2b_kernel(
    const int* __restrict__ rowptr, const int* __restrict__ csr,
    const unsigned short* __restrict__ h1b, const float* __restrict__ wl,
    const float* __restrict__ bias, const float* __restrict__ wr,
    float* __restrict__ out, float* __restrict__ bnsum_out, int N) {
  constexpr int K2P = 33;  // mean[16] | root[16] | pad
  __shared__ float As[64 * K2P];
  const int nb = blockIdx.x * 64;
  const int tid = threadIdx.x;

  {  // gather: 4 threads/node, 8B (4 bf16) each, unroll 8
    const int nl = tid >> 2, t = tid & 3;
    const int n = nb + nl;
    float4 acc = make_float4(0.f, 0.f, 0.f, 0.f);
    float sc = 0.f;
    if (n < N) {
      const int r0 = rowptr[n], r1 = rowptr[n + 1];
      int p = r0;
      for (; p + 8 <= r1; p += 8) {
        int s[8];
#pragma unroll
        for (int u = 0; u < 8; ++u) s[u] = csr[p + u];
        uint2 v[8];
#pragma unroll
        for (int u = 0; u < 8; ++u)
          v[u] = *reinterpret_cast<const uint2*>(h1b + (size_t)s[u] * 16 + t * 4);
#pragma unroll
        for (int u = 0; u < 8; ++u) {
          acc.x += bf2f(v[u].x & 0xFFFFu);
          acc.y += bf2f(v[u].x >> 16);
          acc.z += bf2f(v[u].y & 0xFFFFu);
          acc.w += bf2f(v[u].y >> 16);
        }
      }
      for (; p < r1; ++p) {
        uint2 v = *reinterpret_cast<const uint2*>(h1b + (size_t)csr[p] * 16 + t * 4);
        acc.x += bf2f(v.x & 0xFFFFu);
        acc.y += bf2f(v.x >> 16);
        acc.z += bf2f(v.y & 0xFFFFu);
        acc.w += bf2f(v.y >> 16);
      }
      sc = 1.0f / fmaxf((float)(r1 - r0), 1.0f);
    }
    As[nl * K2P + t * 4 + 0] = acc.x * sc;
    As[nl * K2P + t * 4 + 1] = acc.y * sc;
    As[nl * K2P + t * 4 + 2] = acc.z * sc;
    As[nl * K2P + t * 4 + 3] = acc.w * sc;
  }

  // stage root rows (post-BN bf16 -> fp32)
  if (tid < 128) {
    int nl = tid >> 1, half = tid & 1;
    int n = nb + nl;
    uint4 u = make_uint4(0, 0, 0, 0);
    if (n < N) u = *reinterpret_cast<const uint4*>(h1b + (size_t)n * 16 + half * 8);
    float* d = &As[nl * K2P + 16 + half * 8];
    d[0] = bf2f(u.x & 0xFFFFu); d[1] = bf2f(u.x >> 16);
    d[2] = bf2f(u.y & 0xFFFFu); d[3] = bf2f(u.y >> 16);
    d[4] = bf2f(u.z & 0xFFFFu); d[5] = bf2f(u.z >> 16);
    d[6] = bf2f(u.w & 0xFFFFu); d[7] = bf2f(u.w >> 16);
  }
  __syncthreads();

  const int ty = tid >> 4, tx = tid & 15;
  const int j0 = tx * 4;
  float acc[4][4];
#pragma unroll
  for (int r = 0; r < 4; ++r)
#pragma unroll
    for (int c = 0; c < 4; ++c) acc[r][c] = 0.f;

  const float* A0 = &As[(ty * 4 + 0) * K2P];
  const float* A1 = &As[(ty * 4 + 1) * K2P];
  const float* A2 = &As[(ty * 4 + 2) * K2P];
  const float* A3 = &As[(ty * 4 + 3) * K2P];

#pragma unroll 4
  for (int k = 0; k < 16; ++k) {  // mean @ w2_l
    const float4 w = *reinterpret_cast<const float4*>(wl + (size_t)k * 64 + j0);
    const float wv[4] = {w.x, w.y, w.z, w.w};
    float a0 = A0[k], a1 = A1[k], a2 = A2[k], a3 = A3[k];
#pragma unroll
    for (int c = 0; c < 4; ++c) {
      acc[0][c] = fmaf(a0, wv[c], acc[0][c]);
      acc[1][c] = fmaf(a1, wv[c], acc[1][c]);
      acc[2][c] = fmaf(a2, wv[c], acc[2][c]);
      acc[3][c] = fmaf(a3, wv[c], acc[3][c]);
    }
  }
#pragma unroll 4
  for (int k = 0; k < 16; ++k) {  // root @ w2_r
    const float4 w = *reinterpret_cast<const float4*>(wr + (size_t)k * 64 + j0);
    const float wv[4] = {w.x, w.y, w.z, w.w};
    float a0 = A0[16 + k], a1 = A1[16 + k], a2 = A2[16 + k], a3 = A3[16 + k];
#pragma unroll
    for (int c = 0; c < 4; ++c) {
      acc[0][c] = fmaf(a0, wv[c], acc[0][c]);
      acc[1][c] = fmaf(a1, wv[c], acc[1][c]);
      acc[2][c] = fmaf(a2, wv[c], acc[2][c]);
      acc[3][c] = fmaf(a3, wv[c], acc[3][c]);
    }
  }

  float bv[4];
#pragma unroll
  for (int c = 0; c < 4; ++c) bv[c] = bias[j0 + c];

  float s[4], q[4];
#pragma unroll
  for (int c = 0; c < 4; ++c) { s[c] = 0.f; q[c] = 0.f; }
#pragma unroll
  for (int r = 0; r < 4; ++r) {
    int n = nb + ty * 4 + r;
    if (n < N) {
#pragma unroll
      for (int c = 0; c < 4; ++c) {
        float v = acc[r][c] + bv[c];
        out[(size_t)n * 64 + j0 + c] = v;
        s[c] += v;
        q[c] += v * v;
      }
    }
  }

  __syncthreads();
  float* sL = As;
  float* qL = As + 16 * 64;
#pragma unroll
  for (int c = 0; c < 4; ++c) {
    sL[ty * 64 + tx * 4 + c] = s[c];
    qL[ty * 64 + tx * 4 + c] = q[c];
  }
  __syncthreads();
  float* bn = bnsum_out + (size_t)(blockIdx.x & 7) * 128;
  for (int f = tid; f < 64; f += 256) {
    float ss = 0.f, qq = 0.f;
#pragma unroll
    for (int t = 0; t < 16; ++t) { ss += sL[t * 64 + f]; qq += qL[t * 64 + f]; }
    atomicAdd(&bn[f], ss);
    atomicAdd(&bn[64 + f], qq);
  }
}

// ================= prep3: bn2 inline; swizzled xh + row-major xlin ===================
__global__ __launch_bounds__(256) void prep3_kernel(const float* __restrict__ h2,
                                                    const float* __restrict__ bnsum2,
                                                    const float* __restrict__ g2,
                                                    const float* __restrict__ be2,
                                                    unsigned short* __restrict__ xh,
                                                    unsigned short* __restrict__ xlin,
                                                    float invN, int N) {
  __shared__ float ab[128];
  const int t = threadIdx.x;
  if (t < 64) {
    float m = 0.f, q = 0.f;
#pragma unroll
    for (int r = 0; r < 8; ++r) { m += bnsum2[r * 128 + t]; q += bnsum2[r * 128 + 64 + t]; }
    m *= invN;
    float var = q * invN - m * m;
    float a = g2[t] * rsqrtf(var + EPSF);
    ab[t] = a;
    ab[64 + t] = be2[t] - m * a;
  }
  __syncthreads();
  const int rg = t >> 7, ku = (t >> 4) & 7, r = t & 15;
  const int n = blockIdx.x * 32 + rg * 16 + r;
  if (n >= N) return;
  const float* hp = h2 + (size_t)n * 64 + ku * 8;
  const float4 v0 = *reinterpret_cast<const float4*>(hp);
  const float4 v1 = *reinterpret_cast<const float4*>(hp + 4);
  const float4 A0 = *reinterpret_cast<const float4*>(&ab[ku * 8]);
  const float4 A1 = *reinterpret_cast<const float4*>(&ab[ku * 8 + 4]);
  const float4 B0 = *reinterpret_cast<const float4*>(&ab[64 + ku * 8]);
  const float4 B1 = *reinterpret_cast<const float4*>(&ab[64 + ku * 8 + 4]);
  float rr[8];
  rr[0] = fmaxf(fmaf(v0.x, A0.x, B0.x), 0.f);
  rr[1] = fmaxf(fmaf(v0.y, A0.y, B0.y), 0.f);
  rr[2] = fmaxf(fmaf(v0.z, A0.z, B0.z), 0.f);
  rr[3] = fmaxf(fmaf(v0.w, A0.w, B0.w), 0.f);
  rr[4] = fmaxf(fmaf(v1.x, A1.x, B1.x), 0.f);
  rr[5] = fmaxf(fmaf(v1.y, A1.y, B1.y), 0.f);
  rr[6] = fmaxf(fmaf(v1.z, A1.z, B1.z), 0.f);
  rr[7] = fmaxf(fmaf(v1.w, A1.w, B1.w), 0.f);
  unsigned int uh[4];
#pragma unroll
  for (int j = 0; j < 4; ++j)
    uh[j] = f2bf(rr[2 * j]) | (f2bf(rr[2 * j + 1]) << 16);
  const size_t off = aswz(n, ku);
  *reinterpret_cast<uint4*>(xh + off) = make_uint4(uh[0], uh[1], uh[2], uh[3]);
  *reinterpret_cast<uint4*>(xlin + (size_t)n * 64 + ku * 8) =
      make_uint4(uh[0], uh[1], uh[2], uh[3]);
}

// ================= convw3: swizzled Bt (hi only) =================
__global__ __launch_bounds__(256) void convw3_kernel(const float* __restrict__ wl,
                                                     const float* __restrict__ wr,
                                                     unsigned short* __restrict__ bth) {
  int idx = blockIdx.x * 256 + threadIdx.x;
  if (idx >= 512 * 16) return;
  const int c = idx >> 4, ku = idx & 15;
  unsigned int uh[4];
#pragma unroll
  for (int jj = 0; jj < 4; ++jj) {
    unsigned int hh[2];
#pragma unroll
    for (int t = 0; t < 2; ++t) {
      int k = ku * 8 + jj * 2 + t;
      float w = (k < 64) ? wl[(size_t)k * 512 + c] : wr[(size_t)(k - 64) * 512 + c];
      hh[t] = f2bf(w);
    }
    uh[jj] = hh[0] | (hh[1] << 16);
  }
  const size_t off = ((size_t)(c >> 4) * 16 + ku) * 128 + (size_t)(c & 15) * 8;
  *reinterpret_cast<uint4*>(bth + off) = make_uint4(uh[0], uh[1], uh[2], uh[3]);
}

// ================= gather-mean: reads row-major xlin (x8 unrolled), swizzled mh ======
__global__ __launch_bounds__(256) void gather_mean_bf16(
    const unsigned short* __restrict__ xlin, const int* __restrict__ rowptr,
    const int* __restrict__ csr, unsigned short* __restrict__ mh, int N) {
  const int t = threadIdx.x;
  const int n = blockIdx.x * 32 + (t >> 3);
  const int ku = t & 7;
  if (n >= N) return;
  float acc[8];
#pragma unroll
  for (int i = 0; i < 8; ++i) acc[i] = 0.f;
  const int r0 = rowptr[n], r1 = rowptr[n + 1];
  int p = r0;
  for (; p + 8 <= r1; p += 8) {
    int s[8];
#pragma unroll
    for (int u = 0; u < 8; ++u) s[u] = csr[p + u];
    uint4 u4[8];
#pragma unroll
    for (int u = 0; u < 8; ++u)
      u4[u] = *reinterpret_cast<const uint4*>(xlin + (size_t)s[u] * 64 + ku * 8);
#pragma unroll
    for (int u = 0; u < 8; ++u) {
      const unsigned int uu[4] = {u4[u].x, u4[u].y, u4[u].z, u4[u].w};
#pragma unroll
      for (int j = 0; j < 4; ++j) {
        acc[2 * j]     += bf2f(uu[j] & 0xFFFFu);
        acc[2 * j + 1] += bf2f(uu[j] >> 16);
      }
    }
  }
  for (; p < r1; ++p) {
    const int s = csr[p];
    const uint4 u = *reinterpret_cast<const uint4*>(xlin + (size_t)s * 64 + ku * 8);
    const unsigned int uu[4] = {u.x, u.y, u.z, u.w};
#pragma unroll
    for (int j = 0; j < 4; ++j) {
      acc[2 * j]     += bf2f(uu[j] & 0xFFFFu);
      acc[2 * j + 1] += bf2f(uu[j] >> 16);
    }
  }
  const float sc = 1.0f / fmaxf((float)(r1 - r0), 1.0f);
  unsigned int oh[4];
#pragma unroll
  for (int j = 0; j < 4; ++j)
    oh[j] = f2bf(acc[2 * j] * sc) | (f2bf(acc[2 * j + 1] * sc) << 16);
  const size_t off = aswz(n, ku);
  *reinterpret_cast<uint4*>(mh + off) = make_uint4(oh[0], oh[1], oh[2], oh[3]);
}

// ================= layer-3 MFMA GEMM: all A-frags hoisted, high reg budget ==========
__global__ __launch_bounds__(256, 2) void mfma3_kernel(
    const unsigned short* __restrict__ mh, const unsigned short* __restrict__ xh,
    const unsigned short* __restrict__ bth, const float* __restrict__ bias,
    const int* __restrict__ batchp, float* __restrict__ bnsum,
    unsigned int* __restrict__ pmax, unsigned int* __restrict__ pmin, int N) {
  __shared__ int gb[64];
  const int tid = threadIdx.x;
  const int nb = blockIdx.x * 64;
  const int colbase = blockIdx.y * 256;
  if (tid < 64) gb[tid] = (nb + tid < N) ? batchp[nb + tid] : 0x7FFFFFFF;
  __syncthreads();

  const int wid = tid >> 6, lane = tid & 63;
  const int l16 = lane & 15, lg = lane >> 4;
  const int wcol = colbase + wid * 64;
  const int rgb = blockIdx.x * 4;

  const int abase = rgb * 1024 + lg * 128 + l16 * 8;
  const int bbase = (wcol >> 4) * 2048 + lg * 128 + l16 * 8;

  // hoist ALL 16 A-fragment loads (one HBM latency round instead of four)
  short8 ah[4][4];
#pragma unroll
  for (int rb = 0; rb < 4; ++rb) {
    ah[0][rb] = *reinterpret_cast<const short8*>(mh + abase + rb * 1024);
    ah[1][rb] = *reinterpret_cast<const short8*>(mh + abase + 512 + rb * 1024);
    ah[2][rb] = *reinterpret_cast<const short8*>(xh + abase + rb * 1024);
    ah[3][rb] = *reinterpret_cast<const short8*>(xh + abase + 512 + rb * 1024);
  }

  f32x4 acc[4][4];
#pragma unroll
  for (int rb = 0; rb < 4; ++rb)
#pragma unroll
    for (int cb = 0; cb < 4; ++cb) acc[rb][cb] = (f32x4){0.f, 0.f, 0.f, 0.f};

#pragma unroll
  for (int ks = 0; ks < 4; ++ks) {
#pragma unroll
    for (int cb = 0; cb < 4; ++cb) {
      const short8 bh = *reinterpret_cast<const short8*>(bth + bbase + cb * 2048 + ks * 512);
#pragma unroll
      for (int rb = 0; rb < 4; ++rb) {
        acc[rb][cb] = __builtin_amdgcn_mfma_f32_16x16x32_bf16(ah[ks][rb], bh, acc[rb][cb], 0, 0, 0);
      }
    }
  }

  float* bn = bnsum + (size_t)(blockIdx.x & 7) * 1024;
  const bool uni = (gb[0] == gb[63]);
  const bool full = (nb + 64 <= N);
  const int g0 = gb[0];

  if (full) {
#pragma unroll
    for (int cb = 0; cb < 4; ++cb) {
      const int col = wcol + cb * 16 + l16;
      const float bv = bias[col];
      float s0 = 0.f, q0 = 0.f, mx0 = -INFINITY, mn0 = INFINITY;
#pragma unroll
      for (int rb = 0; rb < 4; ++rb)
#pragma unroll
        for (int r = 0; r < 4; ++r) {
          const float a = acc[rb][cb][r];
          s0 += a;
          q0 = fmaf(a, a, q0);
          mx0 = fmaxf(mx0, a);
          mn0 = fminf(mn0, a);
        }
      s0 += __shfl_xor(s0, 16); s0 += __shfl_xor(s0, 32);
      q0 += __shfl_xor(q0, 16); q0 += __shfl_xor(q0, 32);
      if (lane < 16) {
        atomicAdd(&bn[col], fmaf(64.f, bv, s0));
        atomicAdd(&bn[512 + col], q0 + 2.f * bv * s0 + 64.f * bv * bv);
      }
      if (uni) {
        mx0 = fmaxf(mx0, __shfl_xor(mx0, 16)); mx0 = fmaxf(mx0, __shfl_xor(mx0, 32));
        mn0 = fminf(mn0, __shfl_xor(mn0, 16)); mn0 = fminf(mn0, __shfl_xor(mn0, 32));
        if (lane < 16) {
          atomicMax(&pmax[(size_t)g0 * 512 + col], enc_key(mx0 + bv));
          atomicMin(&pmin[(size_t)g0 * 512 + col], enc_key(mn0 + bv));
        }
      } else {
        int curg = -1;
        float rmx = -INFINITY, rmn = INFINITY;
#pragma unroll
        for (int rb = 0; rb < 4; ++rb)
#pragma unroll
          for (int r = 0; r < 4; ++r) {
            const int row = rb * 16 + lg * 4 + r;
            const int g = gb[row];
            if (g != curg) {
              if (curg >= 0) {
                atomicMax(&pmax[(size_t)curg * 512 + col], enc_key(rmx + bv));
                atomicMin(&pmin[(size_t)curg * 512 + col], enc_key(rmn + bv));
              }
              curg = g; rmx = -INFINITY; rmn = INFINITY;
            }
            const float a = acc[rb][cb][r];
            rmx = fmaxf(rmx, a); rmn = fminf(rmn, a);
          }
        if (curg >= 0) {
          atomicMax(&pmax[(size_t)curg * 512 + col], enc_key(rmx + bv));
          atomicMin(&pmin[(size_t)curg * 512 + col], enc_key(rmn + bv));
        }
      }
    }
  } else {
#pragma unroll
    for (int cb = 0; cb < 4; ++cb) {
      const int col = wcol + cb * 16 + l16;
      const float bv = bias[col];
      float s = 0.f, q = 0.f;
#pragma unroll
      for (int rb = 0; rb < 4; ++rb)
#pragma unroll
        for (int r = 0; r < 4; ++r) {
          const int row = rb * 16 + lg * 4 + r;
          float v = acc[rb][cb][r] + bv;
          acc[rb][cb][r] = v;
          if (nb + row < N) {
            s += v; q += v * v;
          }
        }
      s += __shfl_xor(s, 16); s += __shfl_xor(s, 32);
      q += __shfl_xor(q, 16); q += __shfl_xor(q, 32);
      if (lane < 16) {
        atomicAdd(&bn[col], s);
        atomicAdd(&bn[512 + col], q);
      }
      int curg = -1;
      float rmx = -INFINITY, rmn = INFINITY;
#pragma unroll
      for (int rb = 0; rb < 4; ++rb)
#pragma unroll
        for (int r = 0; r < 4; ++r) {
          const int row = rb * 16 + lg * 4 + r;
          const int g = gb[row];
          if (g != curg) {
            if (curg >= 0 && curg != 0x7FFFFFFF) {
              atomicMax(&pmax[(size_t)curg * 512 + col], enc_key(rmx));
              atomicMin(&pmin[(size_t)curg * 512 + col], enc_key(rmn));
            }
            curg = g; rmx = -INFINITY; rmn = INFINITY;
          }
          if (g != 0x7FFFFFFF) {
            const float v = acc[rb][cb][r];
            rmx = fmaxf(rmx, v); rmn = fminf(rmn, v);
          }
        }
      if (curg >= 0 && curg != 0x7FFFFFFF) {
        atomicMax(&pmax[(size_t)curg * 512 + col], enc_key(rmx));
        atomicMin(&pmin[(size_t)curg * 512 + col], enc_key(rmn));
      }
    }
  }
}

// ================= MLP head (bn3 inline; decodes pooled keys, BN3+ReLU) ==============
__global__ __launch_bounds__(256) void head_kernel(const unsigned int* __restrict__ pmax,
                                                   const unsigned int* __restrict__ pmin,
                                                   const float* __restrict__ bnsum3,
                                                   const float* __restrict__ g3,
                                                   const float* __restrict__ be3,
                                                   const float* __restrict__ w1,
                                                   const float* __restrict__ b1,
                                                   const float* __restrict__ w2,
                                                   const float* __restrict__ b2,
                                                   float* __restrict__ out, float invN) {
  __shared__ float pr[512];
  __shared__ float hid[256];
  int g = blockIdx.x;
  int t = threadIdx.x;
  for (int i = t; i < 512; i += 256) {
    float m = 0.f, q = 0.f;
#pragma unroll
    for (int r = 0; r < 8; ++r) { m += bnsum3[r * 1024 + i]; q += bnsum3[r * 1024 + 512 + i]; }
    m *= invN;
    float var = q * invN - m * m;
    float a = g3[i] * rsqrtf(var + EPSF);
    float b = be3[i] - m * a;
    float v = (a >= 0.f) ? dec_key(pmax[(size_t)g * 512 + i])
                         : dec_key(pmin[(size_t)g * 512 + i]);
    pr[i] = fmaxf(fmaf(v, a, b), 0.f);
  }
  __syncthreads();
  float acc = b1[t];
  for (int i = 0; i < 512; ++i) acc = fmaf(pr[i], w1[(size_t)i * 256 + t], acc);
  hid[t] = fmaxf(acc, 0.f);
  __syncthreads();
  if (t < 10) {
    float o = b2[t];
    for (int j = 0; j < 256; ++j) o = fmaf(hid[j], w2[(size_t)j * 10 + t], o);
    out[(size_t)g * 10 + t] = o;
  }
}

extern "C" void kernel_launch(void* const* d_in, const int* in_sizes, int n_in,
                              void* d_out, int out_size, void* d_ws, size_t ws_size,
                              hipStream_t stream) {
  const float* x    = (const float*)d_in[0];
  const int*   ei   = (const int*)d_in[1];
  const int*   batch= (const int*)d_in[2];
  const float* w1_l = (const float*)d_in[3];
  const float* b1   = (const float*)d_in[4];
  const float* w1_r = (const float*)d_in[5];
  const float* w2_l = (const float*)d_in[6];
  const float* b2   = (const float*)d_in[7];
  const float* w2_r = (const float*)d_in[8];
  const float* w3_l = (const float*)d_in[9];
  const float* b3   = (const float*)d_in[10];
  const float* w3_r = (const float*)d_in[11];
  const float* g1   = (const float*)d_in[12];
  const float* be1  = (const float*)d_in[13];
  const float* g2   = (const float*)d_in[14];
  const float* be2  = (const float*)d_in[15];
  const float* g3   = (const float*)d_in[16];
  const float* be3  = (const float*)d_in[17];
  const float* wl1  = (const float*)d_in[18];
  const float* bl1  = (const float*)d_in[19];
  const float* wl2  = (const float*)d_in[20];
  const float* bl2  = (const float*)d_in[21];

  const int N = in_sizes[0] / 32;
  const int E = in_sizes[1] / 2;
  const int* src  = ei;
  const int* dstp = ei + E;
  float* outp = (float*)d_out;

  const int gx3 = (N + 63) / 64;
  const int Npad = gx3 * 64;
  const int nbuck = (N + 511) >> 9;  // <=256 for N<=131072

  size_t off = 0;
  auto alloc = [&](size_t bytes) -> void* {
    void* p = (char*)d_ws + off;
    off += (bytes + 255) & ~(size_t)255;
    return p;
  };
  int*   rowptr = (int*)alloc(((size_t)N + 1) * 4);
  int*   csr    = (int*)alloc((size_t)E * 4);
  int*   bcnt   = (int*)alloc(256 * 4);
  int*   bbase  = (int*)alloc(257 * 4);
  int*   bcur   = (int*)alloc(256 * 4);
  unsigned int* ebuf = (unsigned int*)alloc((size_t)E * 4);
  float* t1     = (float*)alloc((size_t)N * 16 * 4);
  float* h1     = (float*)alloc((size_t)N * 16 * 4);
  unsigned short* h1b = (unsigned short*)alloc((size_t)N * 16 * 2);
  float* h2     = (float*)alloc((size_t)N * 64 * 4);
  unsigned short* xh = (unsigned short*)alloc((size_t)Npad * 64 * 2);
  unsigned short* mh = (unsigned short*)alloc((size_t)Npad * 64 * 2);
  unsigned short* xlin = (unsigned short*)alloc((size_t)N * 64 * 2);
  unsigned short* bth = (unsigned short*)alloc(512 * 128 * 2);
  float* bnsum1 = (float*)alloc(8 * 32 * 4);
  float* bnsum2 = (float*)alloc(8 * 128 * 4);
  float* bnsum3 = (float*)alloc(8 * 1024 * 4);
  unsigned int* pmax = (unsigned int*)alloc((size_t)NUM_GRAPHS * 512 * 4);
  unsigned int* pmin = (unsigned int*)alloc((size_t)NUM_GRAPHS * 512 * 4);
  (void)ws_size;

  const float invN = 1.0f / (float)N;

  // ---------- consolidated init (bcnt, bnsums, pooled keys) ----------
  init_kernel<<<(NUM_GRAPHS * 512 + 255) / 256, 256, 0, stream>>>(
      bcnt, bnsum1, bnsum2, bnsum3, pmax, pmin);

  // ---------- CSR build: bhist -> bscan -> bucketA(packed) -> bucketCSR ----------
  bhist_kernel<<<(E + 8191) / 8192, 256, 0, stream>>>(dstp, bcnt, E);
  bscan_kernel<<<1, 256, 0, stream>>>(bcnt, bbase, bcur, E);
  bucketA_kernel<<<(E + 8191) / 8192, 256, 0, stream>>>(src, dstp, bcur, ebuf, E);
  bucketCSR_kernel<<<nbuck, 256, 0, stream>>>(ebuf, bbase, rowptr, csr, N, E);

  convw3_kernel<<<(512 * 16 + 255) / 256, 256, 0, stream>>>(w3_l, w3_r, bth);

  // zero the pad rows of the swizzled planes (contiguous tail when N%16==0)
  if (Npad > N && (N & 15) == 0) {
    const size_t padBytes = (size_t)(Npad - N) * 64 * 2;
    hipMemsetAsync(xh + (size_t)N * 64, 0, padBytes, stream);
    hipMemsetAsync(mh + (size_t)N * 64, 0, padBytes, stream);
  }

  // ---------- layer 1: 32 -> 16 (pre-projected mean) ----------
  proj1_kernel<<<(N + 255) / 256, 256, 0, stream>>>(x, w1_l, t1, N);
  linear1_kernel<<<(N + 63) / 64, 256, 0, stream>>>(
      rowptr, csr, t1, x, b1, w1_r, h1, bnsum1, N);

  // ---------- layer 2: 16 -> 64 (bn1 inline in prep2; bf16 gather) ----------
  prep2_kernel<<<(N + 255) / 256, 256, 0, stream>>>(h1, bnsum1, g1, be1, h1b, invN, N);
  linear2b_kernel<<<(N + 63) / 64, 256, 0, stream>>>(
      rowptr, csr, h1b, w2_l, b2, w2_r, h2, bnsum2, N);

  // ---------- layer 3: 64 -> 512 via MFMA (bn2 inline in prep3) ----------
  prep3_kernel<<<(N + 31) / 32, 256, 0, stream>>>(h2, bnsum2, g2, be2, xh, xlin, invN, N);
  gather_mean_bf16<<<(N + 31) / 32, 256, 0, stream>>>(xlin, rowptr, csr, mh, N);
  mfma3_kernel<<<dim3(gx3, 2), 256, 0, stream>>>(
      mh, xh, bth, b3, batch, bnsum3, pmax, pmin, N);

  // ---------- head (bn3 inline) ----------
  head_kernel<<<NUM_GRAPHS, 256, 0, stream>>>(
      pmax, pmin, bnsum3, g3, be3, wl1, bl1, wl2, bl2, outp, invN);
}

// Round 20
// 242.462 us; speedup vs baseline: 1.1412x; 1.0019x over previous
//
#include <hip/hip_runtime.h>
#include <hip/hip_bf16.h>
#include <cstdint>

#define NUM_GRAPHS 128
constexpr float EPSF = 1e-5f;

using short8 = __attribute__((ext_vector_type(8))) short;
using f32x4  = __attribute__((ext_vector_type(4))) float;

// order-preserving float<->uint key (works for negatives)
__device__ __forceinline__ unsigned int enc_key(float f) {
  unsigned int b = __float_as_uint(f);
  return (b & 0x80000000u) ? ~b : (b | 0x80000000u);
}
__device__ __forceinline__ float dec_key(unsigned int k) {
  return __uint_as_float((k & 0x80000000u) ? (k ^ 0x80000000u) : ~k);
}

// manual bf16 RNE conversion (finite values)
__device__ __forceinline__ unsigned int f2bf(float v) {
  unsigned int u = __float_as_uint(v);
  u += 0x7FFFu + ((u >> 16) & 1u);
  return (u >> 16) & 0xFFFFu;
}
__device__ __forceinline__ float bf2f(unsigned int h) {
  return __uint_as_float(h << 16);
}

// swizzled A-plane offset (plane = N x 64 bf16):
//   off(n, f) = (n>>4)*1024 + (f>>3)*128 + (n&15)*8 + (f&7)
__device__ __forceinline__ size_t aswz(int n, int kunit) {
  return ((size_t)(n >> 4) * 8 + kunit) * 128 + (size_t)(n & 15) * 8;
}

__device__ __forceinline__ float4 bnrelu4(float4 v, const float4 A, const float4 B) {
  v.x = fmaxf(fmaf(v.x, A.x, B.x), 0.f);
  v.y = fmaxf(fmaf(v.y, A.y, B.y), 0.f);
  v.z = fmaxf(fmaf(v.z, A.z, B.z), 0.f);
  v.w = fmaxf(fmaf(v.w, A.w, B.w), 0.f);
  return v;
}

// ================= consolidated init: bcnt=0, bnsums=0, pooled keys ==================
__global__ __launch_bounds__(256) void init_kernel(int* __restrict__ bcnt,
                                                   float* __restrict__ bnsum1,
                                                   float* __restrict__ bnsum2,
                                                   float* __restrict__ bnsum3,
                                                   unsigned int* __restrict__ pmax,
                                                   unsigned int* __restrict__ pmin) {
  const int i = blockIdx.x * 256 + threadIdx.x;  // grid covers 65536
  if (i < 256) bcnt[i] = 0;
  if (i < 8 * 32) bnsum1[i] = 0.f;
  if (i < 8 * 128) bnsum2[i] = 0.f;
  if (i < 8 * 1024) bnsum3[i] = 0.f;
  if (i < NUM_GRAPHS * 512) {
    pmax[i] = 0x007FFFFFu;
    pmin[i] = 0xFF800000u;
  }
}

// ================= CSR build (bucketed; bucket = dst>>9, <=256 buckets) =================

__global__ __launch_bounds__(256) void bhist_kernel(const int* __restrict__ dst,
                                                    int* __restrict__ bcnt, int E) {
  __shared__ int hist[256];
  const int t = threadIdx.x;
  const int e0 = blockIdx.x * 8192;
  const int e1 = min(e0 + 8192, E);
  hist[t] = 0;
  __syncthreads();
  for (int e = e0 + t; e < e1; e += 256) atomicAdd(&hist[dst[e] >> 9], 1);
  __syncthreads();
  if (hist[t]) atomicAdd(&bcnt[t], hist[t]);
}

__global__ void bscan_kernel(const int* __restrict__ bcnt, int* __restrict__ bbase,
                             int* __restrict__ bcur, int E) {
  __shared__ int ts[256];
  const int t = threadIdx.x;
  int v = bcnt[t];
  ts[t] = v;
  __syncthreads();
  for (int off = 1; off < 256; off <<= 1) {
    int add = (t >= off) ? ts[t - off] : 0;
    __syncthreads();
    ts[t] += add;
    __syncthreads();
  }
  int excl = ts[t] - v;
  bbase[t] = excl;
  bcur[t] = excl;
  if (t == 255) bbase[256] = E;
}

// pass A: chunk edges, LDS-histogram by bucket, reserve, write packed src|(localdst<<23)
__global__ __launch_bounds__(256) void bucketA_kernel(const int* __restrict__ src,
                                                      const int* __restrict__ dst,
                                                      int* __restrict__ bcur,
                                                      unsigned int* __restrict__ ebuf, int E) {
  __shared__ int hist[256];
  __shared__ int base[256];
  const int t = threadIdx.x;
  const int e0 = blockIdx.x * 8192;
  const int e1 = min(e0 + 8192, E);
  hist[t] = 0;
  __syncthreads();
  for (int e = e0 + t; e < e1; e += 256) atomicAdd(&hist[dst[e] >> 9], 1);
  __syncthreads();
  int c = hist[t];
  base[t] = c ? atomicAdd(&bcur[t], c) : 0;
  hist[t] = 0;
  __syncthreads();
  for (int e = e0 + t; e < e1; e += 256) {
    int d = dst[e];
    int b = d >> 9;
    int p = base[b] + atomicAdd(&hist[b], 1);
    ebuf[p] = (unsigned int)src[e] | ((unsigned int)(d & 511) << 23);
  }
}

// one block per bucket: LDS-stage edges, histogram+scan -> rowptr slice, scatter csr.
__global__ __launch_bounds__(256) void bucketCSR_kernel(
    const unsigned int* __restrict__ ebufp, const int* __restrict__ bbase,
    int* __restrict__ rowptr, int* __restrict__ csr, int N, int E) {
  __shared__ unsigned int eb[12288];
  __shared__ int hist[512];
  __shared__ int ts[256];
  const int b = blockIdx.x;
  const int t = threadIdx.x;
  const int lo = bbase[b], hi = bbase[b + 1];
  const int cnt = hi - lo;
  const bool stage = (cnt <= 12288);
  hist[t] = 0;
  hist[t + 256] = 0;
  __syncthreads();
  if (stage) {
    for (int i = t; i < cnt; i += 256) {
      unsigned int e = ebufp[lo + i];
      eb[i] = e;
      atomicAdd(&hist[e >> 23], 1);
    }
  } else {
    for (int i = t; i < cnt; i += 256) atomicAdd(&hist[ebufp[lo + i] >> 23], 1);
  }
  __syncthreads();
  const int h0 = hist[2 * t], h1 = hist[2 * t + 1];
  const int psum = h0 + h1;
  ts[t] = psum;
  __syncthreads();
  for (int off = 1; off < 256; off <<= 1) {
    int add = (t >= off) ? ts[t - off] : 0;
    __syncthreads();
    ts[t] += add;
    __syncthreads();
  }
  const int pexcl = ts[t] - psum;
  hist[2 * t] = lo + pexcl;
  hist[2 * t + 1] = lo + pexcl + h0;
  __syncthreads();
  const int nbase = b << 9;
  if (nbase + 2 * t < N) rowptr[nbase + 2 * t] = hist[2 * t];
  if (nbase + 2 * t + 1 < N) rowptr[nbase + 2 * t + 1] = hist[2 * t + 1];
  if (b == 0 && t == 0) rowptr[N] = E;
  __syncthreads();
  if (stage) {
    for (int i = t; i < cnt; i += 256) {
      unsigned int e = eb[i];
      int pos = atomicAdd(&hist[e >> 23], 1);
      csr[pos] = (int)(e & 0x7FFFFFu);
    }
  } else {
    for (int i = t; i < cnt; i += 256) {
      unsigned int e = ebufp[lo + i];
      int pos = atomicAdd(&hist[e >> 23], 1);
      csr[pos] = (int)(e & 0x7FFFFFu);
    }
  }
}

// ================= proj1: t1b = bf16(x @ w1_l)  (N x 32 @ 32 x 16) =================
__global__ __launch_bounds__(256) void proj1_kernel(const float* __restrict__ x,
                                                    const float* __restrict__ wl,
                                                    unsigned short* __restrict__ t1b, int N) {
  __shared__ float w[32 * 16];
  const int t = threadIdx.x;
  if (t < 128) reinterpret_cast<float4*>(w)[t] = reinterpret_cast<const float4*>(wl)[t];
  __syncthreads();
  const int n = blockIdx.x * 256 + t;
  if (n >= N) return;
  float xr[32];
  const float4* xp = reinterpret_cast<const float4*>(x + (size_t)n * 32);
#pragma unroll
  for (int i = 0; i < 8; ++i) {
    float4 v = xp[i];
    xr[4 * i] = v.x; xr[4 * i + 1] = v.y; xr[4 * i + 2] = v.z; xr[4 * i + 3] = v.w;
  }
  float o[16];
#pragma unroll
  for (int j = 0; j < 16; ++j) o[j] = 0.f;
#pragma unroll
  for (int k = 0; k < 32; ++k) {
    float xv = xr[k];
#pragma unroll
    for (int j = 0; j < 16; ++j) o[j] = fmaf(xv, w[k * 16 + j], o[j]);
  }
  unsigned int o2[8];
#pragma unroll
  for (int i = 0; i < 8; ++i)
    o2[i] = f2bf(o[2 * i]) | (f2bf(o[2 * i + 1]) << 16);
  uint4* op = reinterpret_cast<uint4*>(t1b + (size_t)n * 16);
  op[0] = make_uint4(o2[0], o2[1], o2[2], o2[3]);
  op[1] = make_uint4(o2[4], o2[5], o2[6], o2[7]);
}

// ================= linear1: out = mean(t1b) + b1 + x @ w1_r (bf16 gather) ============
__global__ __launch_bounds__(256) void linear1_kernel(
    const int* __restrict__ rowptr, const int* __restrict__ csr,
    const unsigned short* __restrict__ t1b, const float* __restrict__ x,
    const float* __restrict__ bias, const float* __restrict__ wr,
    float* __restrict__ out, float* __restrict__ bnsum_out, int N) {
  constexpr int K2P = 49;  // mean[16] | x[32] | pad
  __shared__ float As[64 * K2P];
  const int nb = blockIdx.x * 64;
  const int tid = threadIdx.x;

  {  // gather mean of t1b: 4 threads/node, 8B (4 bf16) each, unroll 8
    const int nl = tid >> 2, t = tid & 3;
    const int n = nb + nl;
    float4 acc = make_float4(0.f, 0.f, 0.f, 0.f);
    float sc = 0.f;
    if (n < N) {
      const int r0 = rowptr[n], r1 = rowptr[n + 1];
      int p = r0;
      for (; p + 8 <= r1; p += 8) {
        int s[8];
#pragma unroll
        for (int u = 0; u < 8; ++u) s[u] = csr[p + u];
        uint2 v[8];
#pragma unroll
        for (int u = 0; u < 8; ++u)
          v[u] = *reinterpret_cast<const uint2*>(t1b + (size_t)s[u] * 16 + t * 4);
#pragma unroll
        for (int u = 0; u < 8; ++u) {
          acc.x += bf2f(v[u].x & 0xFFFFu);
          acc.y += bf2f(v[u].x >> 16);
          acc.z += bf2f(v[u].y & 0xFFFFu);
          acc.w += bf2f(v[u].y >> 16);
        }
      }
      for (; p < r1; ++p) {
        uint2 v = *reinterpret_cast<const uint2*>(t1b + (size_t)csr[p] * 16 + t * 4);
        acc.x += bf2f(v.x & 0xFFFFu);
        acc.y += bf2f(v.x >> 16);
        acc.z += bf2f(v.y & 0xFFFFu);
        acc.w += bf2f(v.y >> 16);
      }
      sc = 1.0f / fmaxf((float)(r1 - r0), 1.0f);
    }
    As[nl * K2P + t * 4 + 0] = acc.x * sc;
    As[nl * K2P + t * 4 + 1] = acc.y * sc;
    As[nl * K2P + t * 4 + 2] = acc.z * sc;
    As[nl * K2P + t * 4 + 3] = acc.w * sc;
  }

  {  // stage x rows
    for (int idx4 = tid; idx4 < 64 * 8; idx4 += 256) {
      int nl = idx4 >> 3, k4 = idx4 & 7;
      int n = nb + nl;
      float4 v = make_float4(0.f, 0.f, 0.f, 0.f);
      if (n < N) v = reinterpret_cast<const float4*>(x + (size_t)n * 32)[k4];
      As[nl * K2P + 16 + k4 * 4 + 0] = v.x;
      As[nl * K2P + 16 + k4 * 4 + 1] = v.y;
      As[nl * K2P + 16 + k4 * 4 + 2] = v.z;
      As[nl * K2P + 16 + k4 * 4 + 3] = v.w;
    }
  }
  __syncthreads();

  const int ty = tid >> 4, tx = tid & 15;
  float acc[4] = {0.f, 0.f, 0.f, 0.f};
  const float* A0 = &As[(ty * 4 + 0) * K2P + 16];
  const float* A1 = &As[(ty * 4 + 1) * K2P + 16];
  const float* A2 = &As[(ty * 4 + 2) * K2P + 16];
  const float* A3 = &As[(ty * 4 + 3) * K2P + 16];
#pragma unroll 4
  for (int k = 0; k < 32; ++k) {
    float w = wr[(size_t)k * 16 + tx];
    acc[0] = fmaf(A0[k], w, acc[0]);
    acc[1] = fmaf(A1[k], w, acc[1]);
    acc[2] = fmaf(A2[k], w, acc[2]);
    acc[3] = fmaf(A3[k], w, acc[3]);
  }

  const float bv = bias[tx];
  float s = 0.f, q = 0.f;
#pragma unroll
  for (int r = 0; r < 4; ++r) {
    int n = nb + ty * 4 + r;
    if (n < N) {
      float v = acc[r] + As[(ty * 4 + r) * K2P + tx] + bv;
      out[(size_t)n * 16 + tx] = v;
      s += v;
      q += v * v;
    }
  }

  __syncthreads();
  float* sL = As;
  float* qL = As + 16 * 16;
  sL[ty * 16 + tx] = s;
  qL[ty * 16 + tx] = q;
  __syncthreads();
  float* bn = bnsum_out + (size_t)(blockIdx.x & 7) * 32;
  if (tid < 16) {
    float ss = 0.f, qq = 0.f;
#pragma unroll
    for (int t = 0; t < 16; ++t) { ss += sL[t * 16 + tid]; qq += qL[t * 16 + tid]; }
    atomicAdd(&bn[tid], ss);
    atomicAdd(&bn[16 + tid], qq);
  }
}

// ================= prep2: h1b = bf16(relu(bn1(h1))); bn1 computed inline =============
__global__ __launch_bounds__(256) void prep2_kernel(const float* __restrict__ h1,
                                                    const float* __restrict__ bnsum1,
                                                    const float* __restrict__ g1,
                                                    const float* __restrict__ be1,
                                                    unsigned short* __restrict__ h1b,
                                                    float invN, int N) {
  __shared__ float ab[32];
  const int t = threadIdx.x;
  if (t < 16) {
    float m = 0.f, q = 0.f;
#pragma unroll
    for (int r = 0; r < 8; ++r) { m += bnsum1[r * 32 + t]; q += bnsum1[r * 32 + 16 + t]; }
    m *= invN;
    float var = q * invN - m * m;
    float a = g1[t] * rsqrtf(var + EPSF);
    ab[t] = a;
    ab[16 + t] = be1[t] - m * a;
  }
  __syncthreads();
  int n = blockIdx.x * 256 + t;
  if (n >= N) return;
  const float4* hp = reinterpret_cast<const float4*>(h1 + (size_t)n * 16);
  unsigned int o[8];
#pragma unroll
  for (int i = 0; i < 4; ++i) {
    float4 v = hp[i];
    const float4 A = *reinterpret_cast<const float4*>(&ab[i * 4]);
    const float4 B = *reinterpret_cast<const float4*>(&ab[16 + i * 4]);
    v = bnrelu4(v, A, B);
    o[2 * i] = f2bf(v.x) | (f2bf(v.y) << 16);
    o[2 * i + 1] = f2bf(v.z) | (f2bf(v.w) << 16);
  }
  uint4* op = reinterpret_cast<uint4*>(h1b + (size_t)n * 16);
  op[0] = make_uint4(o[0], o[1], o[2], o[3]);
  op[1] = make_uint4(o[4], o[5], o[6], o[7]);
}

// ================= linear2b: h2 = mean(h1b)@w2_l + b2 + h1b@w2_r (bf16 gather) ========
__global__ __launch_bounds__(256) void linear2b_kernel(
    const int* __restrict__ rowptr, const int* __restrict__ csr,
    const unsigned short* __restrict__ h1b, const float* __restrict__ wl,
    const float* __restrict__ bias, const float* __restrict__ wr,
    float* __restrict__ out, float* __restrict__ bnsum_out, int N) {
  constexpr int K2P = 33;  // mean[16] | root[16] | pad
  __shared__ float As[64 * K2P];
  const int nb = blockIdx.x * 64;
  const int tid = threadIdx.x;

  {  // gather: 4 threads/node, 8B (4 bf16) each, unroll 8
    const int nl = tid >> 2, t = tid & 3;
    const int n = nb + nl;
    float4 acc = make_float4(0.f, 0.f, 0.f, 0.f);
    float sc = 0.f;
    if (n < N) {
      const int r0 = rowptr[n], r1 = rowptr[n + 1];
      int p = r0;
      for (; p + 8 <= r1; p += 8) {
        int s[8];
#pragma unroll
        for (int u = 0; u < 8; ++u) s[u] = csr[p + u];
        uint2 v[8];
#pragma unroll
        for (int u = 0; u < 8; ++u)
          v[u] = *reinterpret_cast<const uint2*>(h1b + (size_t)s[u] * 16 + t * 4);
#pragma unroll
        for (int u = 0; u < 8; ++u) {
          acc.x += bf2f(v[u].x & 0xFFFFu);
          acc.y += bf2f(v[u].x >> 16);
          acc.z += bf2f(v[u].y & 0xFFFFu);
          acc.w += bf2f(v[u].y >> 16);
        }
      }
      for (; p < r1; ++p) {
        uint2 v = *reinterpret_cast<const uint2*>(h1b + (size_t)csr[p] * 16 + t * 4);
        acc.x += bf2f(v.x & 0xFFFFu);
        acc.y += bf2f(v.x >> 16);
        acc.z += bf2f(v.y & 0xFFFFu);
        acc.w += bf2f(v.y >> 16);
      }
      sc = 1.0f / fmaxf((float)(r1 - r0), 1.0f);
    }
    As[nl * K2P + t * 4 + 0] = acc.x * sc;
    As[nl * K2P + t * 4 + 1] = acc.y * sc;
    As[nl * K2P + t * 4 + 2] = acc.z * sc;
    As[nl * K2P + t * 4 + 3] = acc.w * sc;
  }

  // stage root rows (post-BN bf16 -> fp32)
  if (tid < 128) {
    int nl = tid >> 1, half = tid & 1;
    int n = nb + nl;
    uint4 u = make_uint4(0, 0, 0, 0);
    if (n < N) u = *reinterpret_cast<const uint4*>(h1b + (size_t)n * 16 + half * 8);
    float* d = &As[nl * K2P + 16 + half * 8];
    d[0] = bf2f(u.x & 0xFFFFu); d[1] = bf2f(u.x >> 16);
    d[2] = bf2f(u.y & 0xFFFFu); d[3] = bf2f(u.y >> 16);
    d[4] = bf2f(u.z & 0xFFFFu); d[5] = bf2f(u.z >> 16);
    d[6] = bf2f(u.w & 0xFFFFu); d[7] = bf2f(u.w >> 16);
  }
  __syncthreads();

  const int ty = tid >> 4, tx = tid & 15;
  const int j0 = tx * 4;
  float acc[4][4];
#pragma unroll
  for (int r = 0; r < 4; ++r)
#pragma unroll
    for (int c = 0; c < 4; ++c) acc[r][c] = 0.f;

  const float* A0 = &As[(ty * 4 + 0) * K2P];
  const float* A1 = &As[(ty * 4 + 1) * K2P];
  const float* A2 = &As[(ty * 4 + 2) * K2P];
  const float* A3 = &As[(ty * 4 + 3) * K2P];

#pragma unroll 4
  for (int k = 0; k < 16; ++k) {  // mean @ w2_l
    const float4 w = *reinterpret_cast<const float4*>(wl + (size_t)k * 64 + j0);
    const float wv[4] = {w.x, w.y, w.z, w.w};
    float a0 = A0[k], a1 = A1[k], a2 = A2[k], a3 = A3[k];
#pragma unroll
    for (int c = 0; c < 4; ++c) {
      acc[0][c] = fmaf(a0, wv[c], acc[0][c]);
      acc[1][c] = fmaf(a1, wv[c], acc[1][c]);
      acc[2][c] = fmaf(a2, wv[c], acc[2][c]);
      acc[3][c] = fmaf(a3, wv[c], acc[3][c]);
    }
  }
#pragma unroll 4
  for (int k = 0; k < 16; ++k) {  // root @ w2_r
    const float4 w = *reinterpret_cast<const float4*>(wr + (size_t)k * 64 + j0);
    const float wv[4] = {w.x, w.y, w.z, w.w};
    float a0 = A0[16 + k], a1 = A1[16 + k], a2 = A2[16 + k], a3 = A3[16 + k];
#pragma unroll
    for (int c = 0; c < 4; ++c) {
      acc[0][c] = fmaf(a0, wv[c], acc[0][c]);
      acc[1][c] = fmaf(a1, wv[c], acc[1][c]);
      acc[2][c] = fmaf(a2, wv[c], acc[2][c]);
      acc[3][c] = fmaf(a3, wv[c], acc[3][c]);
    }
  }

  float bv[4];
#pragma unroll
  for (int c = 0; c < 4; ++c) bv[c] = bias[j0 + c];

  float s[4], q[4];
#pragma unroll
  for (int c = 0; c < 4; ++c) { s[c] = 0.f; q[c] = 0.f; }
#pragma unroll
  for (int r = 0; r < 4; ++r) {
    int n = nb + ty * 4 + r;
    if (n < N) {
#pragma unroll
      for (int c = 0; c < 4; ++c) {
        float v = acc[r][c] + bv[c];
        out[(size_t)n * 64 + j0 + c] = v;
        s[c] += v;
        q[c] += v * v;
      }
    }
  }

  __syncthreads();
  float* sL = As;
  float* qL = As + 16 * 64;
#pragma unroll
  for (int c = 0; c < 4; ++c) {
    sL[ty * 64 + tx * 4 + c] = s[c];
    qL[ty * 64 + tx * 4 + c] = q[c];
  }
  __syncthreads();
  float* bn = bnsum_out + (size_t)(blockIdx.x & 7) * 128;
  for (int f = tid; f < 64; f += 256) {
    float ss = 0.f, qq = 0.f;
#pragma unroll
    for (int t = 0; t < 16; ++t) { ss += sL[t * 64 + f]; qq += qL[t * 64 + f]; }
    atomicAdd(&bn[f], ss);
    atomicAdd(&bn[64 + f], qq);
  }
}

// ================= prep3: bn2 inline; swizzled xh + row-major xlin ===================
__global__ __launch_bounds__(256) void prep3_kernel(const float* __restrict__ h2,
                                                    const float* __restrict__ bnsum2,
                                                    const float* __restrict__ g2,
                                                    const float* __restrict__ be2,
                                                    unsigned short* __restrict__ xh,
                                                    unsigned short* __restrict__ xlin,
                                                    float invN, int N) {
  __shared__ float ab[128];
  const int t = threadIdx.x;
  if (t < 64) {
    float m = 0.f, q = 0.f;
#pragma unroll
    for (int r = 0; r < 8; ++r) { m += bnsum2[r * 128 + t]; q += bnsum2[r * 128 + 64 + t]; }
    m *= invN;
    float var = q * invN - m * m;
    float a = g2[t] * rsqrtf(var + EPSF);
    ab[t] = a;
    ab[64 + t] = be2[t] - m * a;
  }
  __syncthreads();
  const int rg = t >> 7, ku = (t >> 4) & 7, r = t & 15;
  const int n = blockIdx.x * 32 + rg * 16 + r;
  if (n >= N) return;
  const float* hp = h2 + (size_t)n * 64 + ku * 8;
  const float4 v0 = *reinterpret_cast<const float4*>(hp);
  const float4 v1 = *reinterpret_cast<const float4*>(hp + 4);
  const float4 A0 = *reinterpret_cast<const float4*>(&ab[ku * 8]);
  const float4 A1 = *reinterpret_cast<const float4*>(&ab[ku * 8 + 4]);
  const float4 B0 = *reinterpret_cast<const float4*>(&ab[64 + ku * 8]);
  const float4 B1 = *reinterpret_cast<const float4*>(&ab[64 + ku * 8 + 4]);
  float rr[8];
  rr[0] = fmaxf(fmaf(v0.x, A0.x, B0.x), 0.f);
  rr[1] = fmaxf(fmaf(v0.y, A0.y, B0.y), 0.f);
  rr[2] = fmaxf(fmaf(v0.z, A0.z, B0.z), 0.f);
  rr[3] = fmaxf(fmaf(v0.w, A0.w, B0.w), 0.f);
  rr[4] = fmaxf(fmaf(v1.x, A1.x, B1.x), 0.f);
  rr[5] = fmaxf(fmaf(v1.y, A1.y, B1.y), 0.f);
  rr[6] = fmaxf(fmaf(v1.z, A1.z, B1.z), 0.f);
  rr[7] = fmaxf(fmaf(v1.w, A1.w, B1.w), 0.f);
  unsigned int uh[4];
#pragma unroll
  for (int j = 0; j < 4; ++j)
    uh[j] = f2bf(rr[2 * j]) | (f2bf(rr[2 * j + 1]) << 16);
  const size_t off = aswz(n, ku);
  *reinterpret_cast<uint4*>(xh + off) = make_uint4(uh[0], uh[1], uh[2], uh[3]);
  *reinterpret_cast<uint4*>(xlin + (size_t)n * 64 + ku * 8) =
      make_uint4(uh[0], uh[1], uh[2], uh[3]);
}

// ================= convw3: swizzled Bt (hi only) =================
__global__ __launch_bounds__(256) void convw3_kernel(const float* __restrict__ wl,
                                                     const float* __restrict__ wr,
                                                     unsigned short* __restrict__ bth) {
  int idx = blockIdx.x * 256 + threadIdx.x;
  if (idx >= 512 * 16) return;
  const int c = idx >> 4, ku = idx & 15;
  unsigned int uh[4];
#pragma unroll
  for (int jj = 0; jj < 4; ++jj) {
    unsigned int hh[2];
#pragma unroll
    for (int t = 0; t < 2; ++t) {
      int k = ku * 8 + jj * 2 + t;
      float w = (k < 64) ? wl[(size_t)k * 512 + c] : wr[(size_t)(k - 64) * 512 + c];
      hh[t] = f2bf(w);
    }
    uh[jj] = hh[0] | (hh[1] << 16);
  }
  const size_t off = ((size_t)(c >> 4) * 16 + ku) * 128 + (size_t)(c & 15) * 8;
  *reinterpret_cast<uint4*>(bth + off) = make_uint4(uh[0], uh[1], uh[2], uh[3]);
}

// ================= gather-mean: reads row-major xlin (x8 unrolled), swizzled mh ======
__global__ __launch_bounds__(256) void gather_mean_bf16(
    const unsigned short* __restrict__ xlin, const int* __restrict__ rowptr,
    const int* __restrict__ csr, unsigned short* __restrict__ mh, int N) {
  const int t = threadIdx.x;
  const int n = blockIdx.x * 32 + (t >> 3);
  const int ku = t & 7;
  if (n >= N) return;
  float acc[8];
#pragma unroll
  for (int i = 0; i < 8; ++i) acc[i] = 0.f;
  const int r0 = rowptr[n], r1 = rowptr[n + 1];
  int p = r0;
  for (; p + 8 <= r1; p += 8) {
    int s[8];
#pragma unroll
    for (int u = 0; u < 8; ++u) s[u] = csr[p + u];
    uint4 u4[8];
#pragma unroll
    for (int u = 0; u < 8; ++u)
      u4[u] = *reinterpret_cast<const uint4*>(xlin + (size_t)s[u] * 64 + ku * 8);
#pragma unroll
    for (int u = 0; u < 8; ++u) {
      const unsigned int uu[4] = {u4[u].x, u4[u].y, u4[u].z, u4[u].w};
#pragma unroll
      for (int j = 0; j < 4; ++j) {
        acc[2 * j]     += bf2f(uu[j] & 0xFFFFu);
        acc[2 * j + 1] += bf2f(uu[j] >> 16);
      }
    }
  }
  for (; p < r1; ++p) {
    const int s = csr[p];
    const uint4 u = *reinterpret_cast<const uint4*>(xlin + (size_t)s * 64 + ku * 8);
    const unsigned int uu[4] = {u.x, u.y, u.z, u.w};
#pragma unroll
    for (int j = 0; j < 4; ++j) {
      acc[2 * j]     += bf2f(uu[j] & 0xFFFFu);
      acc[2 * j + 1] += bf2f(uu[j] >> 16);
    }
  }
  const float sc = 1.0f / fmaxf((float)(r1 - r0), 1.0f);
  unsigned int oh[4];
#pragma unroll
  for (int j = 0; j < 4; ++j)
    oh[j] = f2bf(acc[2 * j] * sc) | (f2bf(acc[2 * j + 1] * sc) << 16);
  const size_t off = aswz(n, ku);
  *reinterpret_cast<uint4*>(mh + off) = make_uint4(oh[0], oh[1], oh[2], oh[3]);
}

// ================= layer-3 MFMA GEMM: all A-frags hoisted, high reg budget ==========
__global__ __launch_bounds__(256, 2) void mfma3_kernel(
    const unsigned short* __restrict__ mh, const unsigned short* __restrict__ xh,
    const unsigned short* __restrict__ bth, const float* __restrict__ bias,
    const int* __restrict__ batchp, float* __restrict__ bnsum,
    unsigned int* __restrict__ pmax, unsigned int* __restrict__ pmin, int N) {
  __shared__ int gb[64];
  const int tid = threadIdx.x;
  const int nb = blockIdx.x * 64;
  const int colbase = blockIdx.y * 256;
  if (tid < 64) gb[tid] = (nb + tid < N) ? batchp[nb + tid] : 0x7FFFFFFF;
  __syncthreads();

  const int wid = tid >> 6, lane = tid & 63;
  const int l16 = lane & 15, lg = lane >> 4;
  const int wcol = colbase + wid * 64;
  const int rgb = blockIdx.x * 4;

  const int abase = rgb * 1024 + lg * 128 + l16 * 8;
  const int bbase = (wcol >> 4) * 2048 + lg * 128 + l16 * 8;

  // hoist ALL 16 A-fragment loads (one HBM latency round instead of four)
  short8 ah[4][4];
#pragma unroll
  for (int rb = 0; rb < 4; ++rb) {
    ah[0][rb] = *reinterpret_cast<const short8*>(mh + abase + rb * 1024);
    ah[1][rb] = *reinterpret_cast<const short8*>(mh + abase + 512 + rb * 1024);
    ah[2][rb] = *reinterpret_cast<const short8*>(xh + abase + rb * 1024);
    ah[3][rb] = *reinterpret_cast<const short8*>(xh + abase + 512 + rb * 1024);
  }

  f32x4 acc[4][4];
#pragma unroll
  for (int rb = 0; rb < 4; ++rb)
#pragma unroll
    for (int cb = 0; cb < 4; ++cb) acc[rb][cb] = (f32x4){0.f, 0.f, 0.f, 0.f};

#pragma unroll
  for (int ks = 0; ks < 4; ++ks) {
#pragma unroll
    for (int cb = 0; cb < 4; ++cb) {
      const short8 bh = *reinterpret_cast<const short8*>(bth + bbase + cb * 2048 + ks * 512);
#pragma unroll
      for (int rb = 0; rb < 4; ++rb) {
        acc[rb][cb] = __builtin_amdgcn_mfma_f32_16x16x32_bf16(ah[ks][rb], bh, acc[rb][cb], 0, 0, 0);
      }
    }
  }

  float* bn = bnsum + (size_t)(blockIdx.x & 7) * 1024;
  const bool uni = (gb[0] == gb[63]);
  const bool full = (nb + 64 <= N);
  const int g0 = gb[0];

  if (full) {
#pragma unroll
    for (int cb = 0; cb < 4; ++cb) {
      const int col = wcol + cb * 16 + l16;
      const float bv = bias[col];
      float s0 = 0.f, q0 = 0.f, mx0 = -INFINITY, mn0 = INFINITY;
#pragma unroll
      for (int rb = 0; rb < 4; ++rb)
#pragma unroll
        for (int r = 0; r < 4; ++r) {
          const float a = acc[rb][cb][r];
          s0 += a;
          q0 = fmaf(a, a, q0);
          mx0 = fmaxf(mx0, a);
          mn0 = fminf(mn0, a);
        }
      s0 += __shfl_xor(s0, 16); s0 += __shfl_xor(s0, 32);
      q0 += __shfl_xor(q0, 16); q0 += __shfl_xor(q0, 32);
      if (lane < 16) {
        atomicAdd(&bn[col], fmaf(64.f, bv, s0));
        atomicAdd(&bn[512 + col], q0 + 2.f * bv * s0 + 64.f * bv * bv);
      }
      if (uni) {
        mx0 = fmaxf(mx0, __shfl_xor(mx0, 16)); mx0 = fmaxf(mx0, __shfl_xor(mx0, 32));
        mn0 = fminf(mn0, __shfl_xor(mn0, 16)); mn0 = fminf(mn0, __shfl_xor(mn0, 32));
        if (lane < 16) {
          atomicMax(&pmax[(size_t)g0 * 512 + col], enc_key(mx0 + bv));
          atomicMin(&pmin[(size_t)g0 * 512 + col], enc_key(mn0 + bv));
        }
      } else {
        int curg = -1;
        float rmx = -INFINITY, rmn = INFINITY;
#pragma unroll
        for (int rb = 0; rb < 4; ++rb)
#pragma unroll
          for (int r = 0; r < 4; ++r) {
            const int row = rb * 16 + lg * 4 + r;
            const int g = gb[row];
            if (g != curg) {
              if (curg >= 0) {
                atomicMax(&pmax[(size_t)curg * 512 + col], enc_key(rmx + bv));
                atomicMin(&pmin[(size_t)curg * 512 + col], enc_key(rmn + bv));
              }
              curg = g; rmx = -INFINITY; rmn = INFINITY;
            }
            const float a = acc[rb][cb][r];
            rmx = fmaxf(rmx, a); rmn = fminf(rmn, a);
          }
        if (curg >= 0) {
          atomicMax(&pmax[(size_t)curg * 512 + col], enc_key(rmx + bv));
          atomicMin(&pmin[(size_t)curg * 512 + col], enc_key(rmn + bv));
        }
      }
    }
  } else {
#pragma unroll
    for (int cb = 0; cb < 4; ++cb) {
      const int col = wcol + cb * 16 + l16;
      const float bv = bias[col];
      float s = 0.f, q = 0.f;
#pragma unroll
      for (int rb = 0; rb < 4; ++rb)
#pragma unroll
        for (int r = 0; r < 4; ++r) {
          const int row = rb * 16 + lg * 4 + r;
          float v = acc[rb][cb][r] + bv;
          acc[rb][cb][r] = v;
          if (nb + row < N) {
            s += v; q += v * v;
          }
        }
      s += __shfl_xor(s, 16); s += __shfl_xor(s, 32);
      q += __shfl_xor(q, 16); q += __shfl_xor(q, 32);
      if (lane < 16) {
        atomicAdd(&bn[col], s);
        atomicAdd(&bn[512 + col], q);
      }
      int curg = -1;
      float rmx = -INFINITY, rmn = INFINITY;
#pragma unroll
      for (int rb = 0; rb < 4; ++rb)
#pragma unroll
        for (int r = 0; r < 4; ++r) {
          const int row = rb * 16 + lg * 4 + r;
          const int g = gb[row];
          if (g != curg) {
            if (curg >= 0 && curg != 0x7FFFFFFF) {
              atomicMax(&pmax[(size_t)curg * 512 + col], enc_key(rmx));
              atomicMin(&pmin[(size_t)curg * 512 + col], enc_key(rmn));
            }
            curg = g; rmx = -INFINITY; rmn = INFINITY;
          }
          if (g != 0x7FFFFFFF) {
            const float v = acc[rb][cb][r];
            rmx = fmaxf(rmx, v); rmn = fminf(rmn, v);
          }
        }
      if (curg >= 0 && curg != 0x7FFFFFFF) {
        atomicMax(&pmax[(size_t)curg * 512 + col], enc_key(rmx));
        atomicMin(&pmin[(size_t)curg * 512 + col], enc_key(rmn));
      }
    }
  }
}

// ================= MLP head (bn3 inline; decodes pooled keys, BN3+ReLU) ==============
__global__ __launch_bounds__(256) void head_kernel(const unsigned int* __restrict__ pmax,
                                                   const unsigned int* __restrict__ pmin,
                                                   const float* __restrict__ bnsum3,
                                                   const float* __restrict__ g3,
                                                   const float* __restrict__ be3,
                                                   const float* __restrict__ w1,
                                                   const float* __restrict__ b1,
                                                   const float* __restrict__ w2,
                                                   const float* __restrict__ b2,
                                                   float* __restrict__ out, float invN) {
  __shared__ float pr[512];
  __shared__ float hid[256];
  int g = blockIdx.x;
  int t = threadIdx.x;
  for (int i = t; i < 512; i += 256) {
    float m = 0.f, q = 0.f;
#pragma unroll
    for (int r = 0; r < 8; ++r) { m += bnsum3[r * 1024 + i]; q += bnsum3[r * 1024 + 512 + i]; }
    m *= invN;
    float var = q * invN - m * m;
    float a = g3[i] * rsqrtf(var + EPSF);
    float b = be3[i] - m * a;
    float v = (a >= 0.f) ? dec_key(pmax[(size_t)g * 512 + i])
                         : dec_key(pmin[(size_t)g * 512 + i]);
    pr[i] = fmaxf(fmaf(v, a, b), 0.f);
  }
  __syncthreads();
  float acc = b1[t];
  for (int i = 0; i < 512; ++i) acc = fmaf(pr[i], w1[(size_t)i * 256 + t], acc);
  hid[t] = fmaxf(acc, 0.f);
  __syncthreads();
  if (t < 10) {
    float o = b2[t];
    for (int j = 0; j < 256; ++j) o = fmaf(hid[j], w2[(size_t)j * 10 + t], o);
    out[(size_t)g * 10 + t] = o;
  }
}

extern "C" void kernel_launch(void* const* d_in, const int* in_sizes, int n_in,
                              void* d_out, int out_size, void* d_ws, size_t ws_size,
                              hipStream_t stream) {
  const float* x    = (const float*)d_in[0];
  const int*   ei   = (const int*)d_in[1];
  const int*   batch= (const int*)d_in[2];
  const float* w1_l = (const float*)d_in[3];
  const float* b1   = (const float*)d_in[4];
  const float* w1_r = (const float*)d_in[5];
  const float* w2_l = (const float*)d_in[6];
  const float* b2   = (const float*)d_in[7];
  const float* w2_r = (const float*)d_in[8];
  const float* w3_l = (const float*)d_in[9];
  const float* b3   = (const float*)d_in[10];
  const float* w3_r = (const float*)d_in[11];
  const float* g1   = (const float*)d_in[12];
  const float* be1  = (const float*)d_in[13];
  const float* g2   = (const float*)d_in[14];
  const float* be2  = (const float*)d_in[15];
  const float* g3   = (const float*)d_in[16];
  const float* be3  = (const float*)d_in[17];
  const float* wl1  = (const float*)d_in[18];
  const float* bl1  = (const float*)d_in[19];
  const float* wl2  = (const float*)d_in[20];
  const float* bl2  = (const float*)d_in[21];

  const int N = in_sizes[0] / 32;
  const int E = in_sizes[1] / 2;
  const int* src  = ei;
  const int* dstp = ei + E;
  float* outp = (float*)d_out;

  const int gx3 = (N + 63) / 64;
  const int Npad = gx3 * 64;
  const int nbuck = (N + 511) >> 9;  // <=256 for N<=131072

  size_t off = 0;
  auto alloc = [&](size_t bytes) -> void* {
    void* p = (char*)d_ws + off;
    off += (bytes + 255) & ~(size_t)255;
    return p;
  };
  int*   rowptr = (int*)alloc(((size_t)N + 1) * 4);
  int*   csr    = (int*)alloc((size_t)E * 4);
  int*   bcnt   = (int*)alloc(256 * 4);
  int*   bbase  = (int*)alloc(257 * 4);
  int*   bcur   = (int*)alloc(256 * 4);
  unsigned int* ebuf = (unsigned int*)alloc((size_t)E * 4);
  unsigned short* t1b = (unsigned short*)alloc((size_t)N * 16 * 2);
  float* h1     = (float*)alloc((size_t)N * 16 * 4);
  unsigned short* h1b = (unsigned short*)alloc((size_t)N * 16 * 2);
  float* h2     = (float*)alloc((size_t)N * 64 * 4);
  unsigned short* xh = (unsigned short*)alloc((size_t)Npad * 64 * 2);
  unsigned short* mh = (unsigned short*)alloc((size_t)Npad * 64 * 2);
  unsigned short* xlin = (unsigned short*)alloc((size_t)N * 64 * 2);
  unsigned short* bth = (unsigned short*)alloc(512 * 128 * 2);
  float* bnsum1 = (float*)alloc(8 * 32 * 4);
  float* bnsum2 = (float*)alloc(8 * 128 * 4);
  float* bnsum3 = (float*)alloc(8 * 1024 * 4);
  unsigned int* pmax = (unsigned int*)alloc((size_t)NUM_GRAPHS * 512 * 4);
  unsigned int* pmin = (unsigned int*)alloc((size_t)NUM_GRAPHS * 512 * 4);
  (void)ws_size;

  const float invN = 1.0f / (float)N;

  // ---------- consolidated init (bcnt, bnsums, pooled keys) ----------
  init_kernel<<<(NUM_GRAPHS * 512 + 255) / 256, 256, 0, stream>>>(
      bcnt, bnsum1, bnsum2, bnsum3, pmax, pmin);

  // ---------- CSR build: bhist -> bscan -> bucketA(packed) -> bucketCSR ----------
  bhist_kernel<<<(E + 8191) / 8192, 256, 0, stream>>>(dstp, bcnt, E);
  bscan_kernel<<<1, 256, 0, stream>>>(bcnt, bbase, bcur, E);
  bucketA_kernel<<<(E + 8191) / 8192, 256, 0, stream>>>(src, dstp, bcur, ebuf, E);
  bucketCSR_kernel<<<nbuck, 256, 0, stream>>>(ebuf, bbase, rowptr, csr, N, E);

  convw3_kernel<<<(512 * 16 + 255) / 256, 256, 0, stream>>>(w3_l, w3_r, bth);

  // zero the pad rows of the swizzled planes (contiguous tail when N%16==0)
  if (Npad > N && (N & 15) == 0) {
    const size_t padBytes = (size_t)(Npad - N) * 64 * 2;
    hipMemsetAsync(xh + (size_t)N * 64, 0, padBytes, stream);
    hipMemsetAsync(mh + (size_t)N * 64, 0, padBytes, stream);
  }

  // ---------- layer 1: 32 -> 16 (pre-projected bf16 mean table) ----------
  proj1_kernel<<<(N + 255) / 256, 256, 0, stream>>>(x, w1_l, t1b, N);
  linear1_kernel<<<(N + 63) / 64, 256, 0, stream>>>(
      rowptr, csr, t1b, x, b1, w1_r, h1, bnsum1, N);

  // ---------- layer 2: 16 -> 64 (bn1 inline in prep2; bf16 gather) ----------
  prep2_kernel<<<(N + 255) / 256, 256, 0, stream>>>(h1, bnsum1, g1, be1, h1b, invN, N);
  linear2b_kernel<<<(N + 63) / 64, 256, 0, stream>>>(
      rowptr, csr, h1b, w2_l, b2, w2_r, h2, bnsum2, N);

  // ---------- layer 3: 64 -> 512 via MFMA (bn2 inline in prep3) ----------
  prep3_kernel<<<(N + 31) / 32, 256, 0, stream>>>(h2, bnsum2, g2, be2, xh, xlin, invN, N);
  gather_mean_bf16<<<(N + 31) / 32, 256, 0, stream>>>(xlin, rowptr, csr, mh, N);
  mfma3_kernel<<<dim3(gx3, 2), 256, 0, stream>>>(
      mh, xh, bth, b3, batch, bnsum3, pmax, pmin, N);

  // ---------- head (bn3 inline) ----------
  head_kernel<<<NUM_GRAPHS, 256, 0, stream>>>(
      pmax, pmin, bnsum3, g3, be3, wl1, bl1, wl2, bl2, outp, invN);
}